// Round 7
// baseline (659.682 us; speedup 1.0000x reference)
//
#include <hip/hip_runtime.h>
#include <math.h>

#define HF 100
#define WFD 160
#define CIN 512
#define CONV_C 512
#define NPIX (HF*WFD)           // 16000
#define NBOX (NPIX*9)           // 144000
#define PRE_NMS 6000
#define POST_NMS 300
#define NEGV (-1.0e9f)
#define IMG_H 1600.0f
#define IMG_W 2560.0f
#define NHBINS 32768
#define NWORDS 94               // ceil(6000/64)
#define NSORT 6016              // 94*64

// padded X: 102 rows x 162 cols x 512 ch
#define PR 102
#define PC 162
#define NPAD ((size_t)PR*PC*512)   // 8,460,288 ushorts per array

typedef __attribute__((ext_vector_type(8))) _Float16 half8;
typedef __attribute__((ext_vector_type(4))) float floatx4;

__device__ __forceinline__ unsigned short f2h_hi(float x) {
    _Float16 h = (_Float16)x;
    return __builtin_bit_cast(unsigned short, h);
}
__device__ __forceinline__ unsigned short f2h_lo(float x, unsigned short hbits) {
    _Float16 h = __builtin_bit_cast(_Float16, hbits);
    _Float16 l = (_Float16)((x - (float)h) * 2048.0f);   // scaled residual: stays normal
    return __builtin_bit_cast(unsigned short, l);
}

#define GLL16(g, l) __builtin_amdgcn_global_load_lds( \
    (const __attribute__((address_space(1))) void*)(g), \
    (__attribute__((address_space(3))) void*)(l), 16, 0, 0)

// ---- workspace layout (units: floats) ----
static const size_t OYREG = 0;
static const size_t OXH   = OYREG + (size_t)NPIX * CONV_C;  // Xh ushorts; dead after conv
static const size_t OXL   = OXH + NPAD / 2;                 // Xl ushorts; dead after conv
static const size_t OWH   = OXL + NPAD / 2;                 // fp16 [9][n=512][k=512]
static const size_t OWL   = OWH + (size_t)9*512*512/2;
static const size_t ORAW  = OWL + (size_t)9*512*512/2;
static const size_t ONMS  = ORAW + NBOX;
static const size_t OPY1  = ONMS + NBOX;
static const size_t OPX1  = OPY1 + NBOX;
static const size_t OPY2  = OPX1 + NBOX;
static const size_t OPX2  = OPY2 + NBOX;
static const size_t OHIST = OPX2 + NBOX;                    // 32768 uints
static const size_t OCNT  = OHIST + NHBINS;                 // 4 ints
static const size_t OPAR  = OCNT + 4;                       // 2 ints
static const size_t OCS   = OPAR + 2;                       // 6000
static const size_t OCY1  = OCS + PRE_NMS;
static const size_t OCX1  = OCY1 + PRE_NMS;
static const size_t OCY2  = OCX1 + PRE_NMS;
static const size_t OCX2  = OCY2 + PRE_NMS;
static const size_t OW2H  = OCX2 + PRE_NMS;                 // 48*512 ushorts = 12288 floats
static const size_t OW2L  = OW2H + 12288;
// overlays (written after conv_mfma is done):
static const size_t OMASK = OXH;                            // u64[6016*94]
static const size_t OSY1  = OXL;                            // 6016 each, 5 arrays
static const size_t OSX1  = OSY1 + NSORT;
static const size_t OSY2  = OSX1 + NSORT;
static const size_t OSX2  = OSY2 + NSORT;
static const size_t OSAR  = OSX2 + NSORT;

// ============================================================
// split X (fp32) -> padded fp16 hi + scaled-lo (linear layout)
// ============================================================
__global__ __launch_bounds__(256) void split_x(
    const float* __restrict__ X,
    unsigned short* __restrict__ Xh, unsigned short* __restrict__ Xl)
{
    const int idx = blockIdx.x * 256 + threadIdx.x;
    const int p = idx >> 7;
    const int kq = (idx & 127) * 4;
    const float4 v = *(const float4*)(X + (size_t)p * 512 + kq);
    const int r = p / WFD, c = p % WFD;
    const size_t dst = ((size_t)(r + 1) * PC + (c + 1)) * 512 + kq;
    float vv[4] = { v.x, v.y, v.z, v.w };
    unsigned short h[4], lo[4];
    #pragma unroll
    for (int u = 0; u < 4; ++u) {
        h[u]  = f2h_hi(vv[u]);
        lo[u] = f2h_lo(vv[u], h[u]);
    }
    uint2 ph, pl;
    ph.x = (unsigned)h[0]  | ((unsigned)h[1]  << 16);
    ph.y = (unsigned)h[2]  | ((unsigned)h[3]  << 16);
    pl.x = (unsigned)lo[0] | ((unsigned)lo[1] << 16);
    pl.y = (unsigned)lo[2] | ((unsigned)lo[3] << 16);
    *(uint2*)(Xh + dst) = ph;
    *(uint2*)(Xl + dst) = pl;
}

// ============================================================
// split + transpose W1 [dydx][k][n] fp32 -> Wh/Wl [dydx][n][k] fp16
// ============================================================
__global__ __launch_bounds__(256) void split_w(
    const float* __restrict__ W1,
    unsigned short* __restrict__ Wh, unsigned short* __restrict__ Wl)
{
    __shared__ unsigned short Lh[64 * 64];
    __shared__ unsigned short Ll[64 * 64];
    const int t = threadIdx.x;
    const int dydx = blockIdx.x >> 6;
    const int rem  = blockIdx.x & 63;
    const int k0 = (rem >> 3) * 64, n0 = (rem & 7) * 64;

    #pragma unroll
    for (int i = 0; i < 4; ++i) {
        const int f = t + 256 * i;
        const int row = f >> 4;
        const int cp  = (f & 15) * 4;
        const float4 v = *(const float4*)(W1 + ((size_t)(dydx * 512 + k0 + row)) * 512 + n0 + cp);
        float vv[4] = { v.x, v.y, v.z, v.w };
        #pragma unroll
        for (int u = 0; u < 4; ++u) {
            const unsigned short h = f2h_hi(vv[u]);
            Lh[(cp + u) * 64 + row] = h;
            Ll[(cp + u) * 64 + row] = f2h_lo(vv[u], h);
        }
    }
    __syncthreads();
    const int n  = t >> 2;
    const int kp = (t & 3) * 16;
    const size_t gbase = ((size_t)(dydx * 512 + n0 + n)) * 512 + k0 + kp;
    *(uint4*)(Wh + gbase)     = *(const uint4*)(Lh + n * 64 + kp);
    *(uint4*)(Wh + gbase + 8) = *(const uint4*)(Lh + n * 64 + kp + 8);
    *(uint4*)(Wl + gbase)     = *(const uint4*)(Ll + n * 64 + kp);
    *(uint4*)(Wl + gbase + 8) = *(const uint4*)(Ll + n * 64 + kp + 8);
}

// ============================================================
// split head weights: Wc[512][9] + Wr[512][36] -> [n=48][k=512] fp16 hi/lo
// ============================================================
__global__ __launch_bounds__(256) void split_w2(
    const float* __restrict__ Wc, const float* __restrict__ Wr,
    unsigned short* __restrict__ W2h, unsigned short* __restrict__ W2l)
{
    const int i = blockIdx.x * 256 + threadIdx.x;   // 0..24575
    if (i >= 48 * 512) return;
    const int n = i >> 9, k = i & 511;
    float v = 0.f;
    if (n < 9) v = Wc[k * 9 + n];
    else if (n < 45) v = Wr[k * 36 + (n - 9)];
    const unsigned short h = f2h_hi(v);
    W2h[i] = h;
    W2l[i] = f2h_lo(v, h);
}

// ============================================================
// conv 3x3 512->512, split-fp16 3-pass MFMA.
// r2/r3-VERIFIED structure (bit-exact revert): XOR chunk swizzle keeps
// staging coalesced AND ds_read conflict-free; double-buffered with
// counted vmcnt(8); two barriers per K-step. (r6's single-barrier
// variant is parked until the container failure is understood.)
// ============================================================
__global__ __launch_bounds__(256, 2) void conv_mfma(
    const unsigned short* __restrict__ Xh, const unsigned short* __restrict__ Xl,
    const unsigned short* __restrict__ Wh, const unsigned short* __restrict__ Wl,
    const float* __restrict__ b1,
    unsigned short* __restrict__ Yh, unsigned short* __restrict__ Yl)
{
    __shared__ alignas(16) unsigned short Ah[2][128 * 32];
    __shared__ alignas(16) unsigned short Al[2][128 * 32];
    __shared__ alignas(16) unsigned short Bh[2][128 * 32];
    __shared__ alignas(16) unsigned short Bl[2][128 * 32];

    const int tid = threadIdx.x;
    const int w = tid >> 6, l = tid & 63;
    const int wy = w >> 1, wx = w & 1;

    const int bx = blockIdx.x;
    const int q = bx & 7, s5 = bx >> 3;
    const int tile = (q < 5) ? (q * 16 + s5) : (80 + (q - 5) * 15 + s5);
    const int pm0 = tile * 128, oc0 = blockIdx.y * 128;

    // staging offsets: row = l>>2 (coalesced), chunk XOR-swizzled in-line
    const int swW = ((l & 3) ^ ((l >> 3) & 3)) * 8;   // write-side chunk (ushorts)
    int aoff[2], boff[2], ldsOff[2];
    #pragma unroll
    for (int i = 0; i < 2; ++i) {
        const int m = w * 32 + i * 16 + (l >> 2);
        const int p = pm0 + m;
        const int r = p / WFD, c = p % WFD;
        aoff[i] = ((r + 1) * PC + (c + 1)) * 512 + swW;
        boff[i] = (oc0 + m) * 512 + swW;
        ldsOff[i] = (w * 32 + i * 16) * 32;
    }

    // fragment read offsets: row_in_region = l&15, chunk = (l>>4)^((l>>1)&3)
    const int swR = (((l >> 4) ^ ((l >> 1) & 3))) * 8;
    int afrag[4], bfrag[4];
    #pragma unroll
    for (int i = 0; i < 4; ++i) {
        afrag[i] = (wy * 64 + i * 16 + (l & 15)) * 32 + swR;
        bfrag[i] = (wx * 64 + i * 16 + (l & 15)) * 32 + swR;
    }

    floatx4 acc[4][4], accL[4][4];
    #pragma unroll
    for (int j = 0; j < 4; ++j) {
        const float bv = b1[oc0 + wx * 64 + j * 16 + (l & 15)];
        #pragma unroll
        for (int i = 0; i < 4; ++i) {
            acc[i][j][0] = bv; acc[i][j][1] = bv; acc[i][j][2] = bv; acc[i][j][3] = bv;
            accL[i][j][0] = 0.f; accL[i][j][1] = 0.f; accL[i][j][2] = 0.f; accL[i][j][3] = 0.f;
        }
    }

    #define CSTAGE(bf, dAx, dBx)                                    \
        _Pragma("unroll")                                           \
        for (int i = 0; i < 2; ++i) {                               \
            GLL16(Xh + aoff[i] + (dAx), Ah[bf] + ldsOff[i]);        \
            GLL16(Xl + aoff[i] + (dAx), Al[bf] + ldsOff[i]);        \
            GLL16(Wh + boff[i] + (dBx), Bh[bf] + ldsOff[i]);        \
            GLL16(Wl + boff[i] + (dBx), Bl[bf] + ldsOff[i]);        \
        }

    // prologue: stage step 0 (dydx=0 -> dy=-1,dx=-1; k0=0) into buffer 0
    CSTAGE(0, (-PC - 1) * 512, 0);

    for (int step = 0; step < 144; ++step) {
        const int cur = step & 1;
        if (step < 143) {
            const int s1 = step + 1;
            const int d1 = s1 >> 4;
            const int k1 = (s1 & 15) << 5;
            const int dy = d1 / 3 - 1, dx = d1 % 3 - 1;
            CSTAGE(cur ^ 1, (dy * PC + dx) * 512 + k1, d1 * (512 * 512) + k1);
            asm volatile("s_waitcnt vmcnt(8)" ::: "memory");
        } else {
            asm volatile("s_waitcnt vmcnt(0)" ::: "memory");
        }
        __builtin_amdgcn_s_barrier();
        asm volatile("" ::: "memory");

        const unsigned short* Ac = Ah[cur];
        const unsigned short* Lc = Al[cur];
        const unsigned short* Bc = Bh[cur];
        const unsigned short* Mc = Bl[cur];
        half8 fah[4], fal[4], fbh[4], fbl[4];
        #pragma unroll
        for (int i = 0; i < 4; ++i) {
            fah[i] = *(const half8*)(Ac + afrag[i]);
            fal[i] = *(const half8*)(Lc + afrag[i]);
            fbh[i] = *(const half8*)(Bc + bfrag[i]);
            fbl[i] = *(const half8*)(Mc + bfrag[i]);
        }
        #pragma unroll
        for (int i = 0; i < 4; ++i)
            #pragma unroll
            for (int j = 0; j < 4; ++j) {
                acc[i][j]  = __builtin_amdgcn_mfma_f32_16x16x32_f16(fah[i], fbh[j], acc[i][j], 0, 0, 0);
                accL[i][j] = __builtin_amdgcn_mfma_f32_16x16x32_f16(fal[i], fbh[j], accL[i][j], 0, 0, 0);
                accL[i][j] = __builtin_amdgcn_mfma_f32_16x16x32_f16(fah[i], fbl[j], accL[i][j], 0, 0, 0);
            }
        asm volatile("" ::: "memory");
        __builtin_amdgcn_s_barrier();
    }
    #undef CSTAGE

    // epilogue: ReLU + fp16 hi/lo split + store
    #pragma unroll
    for (int i = 0; i < 4; ++i) {
        const int row0 = pm0 + wy * 64 + i * 16 + (l >> 4) * 4;
        #pragma unroll
        for (int j = 0; j < 4; ++j) {
            const int col = oc0 + wx * 64 + j * 16 + (l & 15);
            #pragma unroll
            for (int r = 0; r < 4; ++r) {
                const float yv = fmaxf(acc[i][j][r] + accL[i][j][r] * 4.8828125e-4f, 0.f);
                const unsigned short h = f2h_hi(yv);
                const size_t o = (size_t)(row0 + r) * 512 + col;
                Yh[o] = h;
                Yl[o] = f2h_lo(yv, h);
            }
        }
    }
}

// ============================================================
// heads as skinny split-fp16 MFMA GEMM (r3-verified, LDS histogram).
// ============================================================
__global__ __launch_bounds__(256) void heads_mfma(
    const unsigned short* __restrict__ Yh, const unsigned short* __restrict__ Yl,
    const unsigned short* __restrict__ W2h, const unsigned short* __restrict__ W2l,
    const float* __restrict__ bc, const float* __restrict__ br,
    const float* __restrict__ anch,
    float* __restrict__ out_scores, float* __restrict__ out_deltas,
    float* __restrict__ rawS, float* __restrict__ nmsS,
    float* __restrict__ pY1, float* __restrict__ pX1,
    float* __restrict__ pY2, float* __restrict__ pX2,
    unsigned int* __restrict__ hist)
{
    __shared__ alignas(16) unsigned short Ah[128 * 32];
    __shared__ alignas(16) unsigned short Al[128 * 32];
    __shared__ alignas(16) unsigned short Bh[48 * 32];
    __shared__ alignas(16) unsigned short Bl[48 * 32];
    __shared__ float Lg[128 * 49];
    __shared__ unsigned int Hh[NHBINS / 2];   // packed u16-pair histogram, 64KB

    const int tid = threadIdx.x;
    const int w = tid >> 6, l = tid & 63;
    const int pm0 = blockIdx.x * 128;

    // zero the LDS histogram (covered by the first k-loop __syncthreads)
    #pragma unroll 4
    for (int i = tid; i < NHBINS / 2; i += 256) Hh[i] = 0u;

    const int swW = ((l & 3) ^ ((l >> 3) & 3)) * 8;
    int aoff[2], ldsOff[2];
    #pragma unroll
    for (int i = 0; i < 2; ++i) {
        const int m = w * 32 + i * 16 + (l >> 2);
        aoff[i] = (pm0 + m) * 512 + swW;
        ldsOff[i] = (w * 32 + i * 16) * 32;
    }
    // B staging: waves 0..2 each cover 16 weight rows
    const int bglb = (w * 16 + (l >> 2)) * 512 + swW;  // valid for w<3
    const int blds = w * 16 * 32;

    const int swR = (((l >> 4) ^ ((l >> 1) & 3))) * 8;
    int afrag[2], bfrag[3];
    #pragma unroll
    for (int i = 0; i < 2; ++i)
        afrag[i] = (w * 32 + i * 16 + (l & 15)) * 32 + swR;
    #pragma unroll
    for (int j = 0; j < 3; ++j)
        bfrag[j] = (j * 16 + (l & 15)) * 32 + swR;

    floatx4 acc[2][3], accL[2][3];
    #pragma unroll
    for (int i = 0; i < 2; ++i)
        #pragma unroll
        for (int j = 0; j < 3; ++j) {
            acc[i][j][0] = 0.f; acc[i][j][1] = 0.f; acc[i][j][2] = 0.f; acc[i][j][3] = 0.f;
            accL[i][j] = acc[i][j];
        }

    for (int k0 = 0; k0 < 512; k0 += 32) {
        __syncthreads();
        #pragma unroll
        for (int i = 0; i < 2; ++i) {
            GLL16(Yh + aoff[i] + k0, Ah + ldsOff[i]);
            GLL16(Yl + aoff[i] + k0, Al + ldsOff[i]);
        }
        if (w < 3) {
            GLL16(W2h + bglb + k0, Bh + blds);
            GLL16(W2l + bglb + k0, Bl + blds);
        }
        __syncthreads();
        half8 fah[2], fal[2], fbh[3], fbl[3];
        #pragma unroll
        for (int i = 0; i < 2; ++i) {
            fah[i] = *(const half8*)(Ah + afrag[i]);
            fal[i] = *(const half8*)(Al + afrag[i]);
        }
        #pragma unroll
        for (int j = 0; j < 3; ++j) {
            fbh[j] = *(const half8*)(Bh + bfrag[j]);
            fbl[j] = *(const half8*)(Bl + bfrag[j]);
        }
        #pragma unroll
        for (int i = 0; i < 2; ++i)
            #pragma unroll
            for (int j = 0; j < 3; ++j) {
                acc[i][j]  = __builtin_amdgcn_mfma_f32_16x16x32_f16(fah[i], fbh[j], acc[i][j], 0, 0, 0);
                accL[i][j] = __builtin_amdgcn_mfma_f32_16x16x32_f16(fal[i], fbh[j], accL[i][j], 0, 0, 0);
                accL[i][j] = __builtin_amdgcn_mfma_f32_16x16x32_f16(fah[i], fbl[j], accL[i][j], 0, 0, 0);
            }
    }

    // logits -> LDS. C/D: col=lane&15, row=(lane>>4)*4+reg
    __syncthreads();
    #pragma unroll
    for (int i = 0; i < 2; ++i) {
        const int prow0 = w * 32 + i * 16 + (l >> 4) * 4;
        #pragma unroll
        for (int j = 0; j < 3; ++j) {
            const int col = j * 16 + (l & 15);
            #pragma unroll
            for (int r = 0; r < 4; ++r)
                Lg[(prow0 + r) * 49 + col] = acc[i][j][r] + accL[i][j][r] * 4.8828125e-4f;
        }
    }
    __syncthreads();

    if (tid < 128) {
        const int p = pm0 + tid;
        float ac[9], arr[36];
        #pragma unroll
        for (int a = 0; a < 9; ++a) ac[a] = Lg[tid * 49 + a] + bc[a];
        #pragma unroll
        for (int j = 0; j < 36; ++j) arr[j] = Lg[tid * 49 + 9 + j] + br[j];

        float m = ac[0];
        #pragma unroll
        for (int a = 1; a < 9; ++a) m = fmaxf(m, ac[a]);
        float s = 0.f, e[9];
        #pragma unroll
        for (int a = 0; a < 9; ++a) { e[a] = expf(ac[a] - m); s += e[a]; }
        #pragma unroll
        for (int a = 0; a < 9; ++a) e[a] = e[a] / s;

        #pragma unroll
        for (int a = 0; a < 9; ++a) out_scores[p * 9 + a] = e[a];
        #pragma unroll
        for (int a = 0; a < 9; ++a)
            *(float4*)(out_deltas + (size_t)p * 36 + 4 * a) =
                make_float4(arr[4*a], arr[4*a+1], arr[4*a+2], arr[4*a+3]);

        #pragma unroll
        for (int a = 0; a < 9; ++a) {
            const float4 an = *(const float4*)(anch + (size_t)p * 36 + 4 * a);
            const float cty = an.x + arr[4*a]   * an.z;
            const float ctx = an.y + arr[4*a+1] * an.w;
            const float szy = an.z * expf(arr[4*a+2]);
            const float szx = an.w * expf(arr[4*a+3]);
            float y1 = fmaxf(cty - 0.5f * szy, 0.f);
            float x1 = fmaxf(ctx - 0.5f * szx, 0.f);
            float y2 = fminf(cty + 0.5f * szy, IMG_H);
            float x2 = fminf(ctx + 0.5f * szx, IMG_W);
            const bool valid = ((y2 - y1) >= 16.f) && ((x2 - x1) >= 16.f);
            const int idx = p * 9 + a;
            rawS[idx] = e[a];
            nmsS[idx] = valid ? e[a] : NEGV;
            pY1[idx] = y1; pX1[idx] = x1; pY2[idx] = y2; pX2[idx] = x2;
            const unsigned b = __float_as_uint(e[a]) >> 15;
            atomicAdd(&Hh[b >> 1], (b & 1) ? 65536u : 1u);
        }
    }

    // flush LDS histogram to global (few hundred nonzero bins per block)
    __syncthreads();
    for (int i = tid; i < NHBINS / 2; i += 256) {
        const unsigned v = Hh[i];
        if (v) {
            const unsigned lo = v & 0xFFFFu;
            const unsigned hi = v >> 16;
            if (lo) atomicAdd(&hist[2 * i],     lo);
            if (hi) atomicAdd(&hist[2 * i + 1], hi);
        }
    }
}

// ============================================================
// select_k: parallel suffix-scan over histogram
// ============================================================
__global__ __launch_bounds__(1024) void select_k(const unsigned int* __restrict__ hist,
                                                 int* __restrict__ params)
{
    __shared__ unsigned int ps[1024];
    const int t = threadIdx.x;
    unsigned int loc[32];
    unsigned int sum = 0;
    #pragma unroll 4
    for (int i = 0; i < 32; ++i) { loc[i] = hist[t * 32 + i]; sum += loc[i]; }
    ps[t] = sum;
    for (int off = 1; off < 1024; off <<= 1) {
        __syncthreads();
        const unsigned int add = (t + off < 1024) ? ps[t + off] : 0u;
        __syncthreads();
        ps[t] += add;
    }
    __syncthreads();
    const unsigned int above = (t < 1023) ? ps[t + 1] : 0u;
    if (above < (unsigned)PRE_NMS && ps[t] >= (unsigned)PRE_NMS) {
        unsigned int cum = above;
        for (int j = 31; j >= 0; --j) {
            const unsigned int h = loc[j];
            if (cum + h >= (unsigned)PRE_NMS) {
                params[0] = t * 32 + j;
                params[1] = PRE_NMS - (int)cum;
                break;
            }
            cum += h;
        }
    }
}

// ============================================================
// compact_k: wave-aggregated position allocation (ballot + leader atomic).
// ============================================================
__global__ void compact_k(const float* __restrict__ rawS, const float* __restrict__ nmsS,
                          const float* __restrict__ pY1, const float* __restrict__ pX1,
                          const float* __restrict__ pY2, const float* __restrict__ pX2,
                          const int* __restrict__ params, int* __restrict__ cnts,
                          float* __restrict__ cS,
                          float* __restrict__ cY1, float* __restrict__ cX1,
                          float* __restrict__ cY2, float* __restrict__ cX2)
{
    const int i = blockIdx.x * 256 + threadIdx.x;
    const int lane = threadIdx.x & 63;
    const bool act = i < NBOX;
    int b = -1;
    if (act) b = (int)(__float_as_uint(rawS[i]) >> 15);
    const int bin = params[0];
    const int need = params[1];
    int pos = -1;

    // case A: strictly above threshold bin -> always taken
    {
        const bool p = act && (b > bin);
        const unsigned long long m = __ballot(p);
        if (p) {
            const int leader = __ffsll(m) - 1;
            int base = 0;
            if (lane == leader) base = atomicAdd(&cnts[0], __popcll(m));
            base = __shfl(base, leader, 64);
            pos = base + __popcll(m & ((1ULL << lane) - 1));
        }
    }
    // case B: threshold bin -> first `need` arrivals taken
    {
        const bool p = act && (b == bin);
        const unsigned long long m = __ballot(p);
        if (p) {
            const int leader = __ffsll(m) - 1;
            int base2 = 0;
            if (lane == leader) base2 = atomicAdd(&cnts[1], __popcll(m));
            base2 = __shfl(base2, leader, 64);
            const int t2 = base2 + __popcll(m & ((1ULL << lane) - 1));
            const bool take = t2 < need;
            const unsigned long long m3 = __ballot(take);
            if (take) {
                const int leader3 = __ffsll(m3) - 1;
                int base3 = 0;
                if (lane == leader3) base3 = atomicAdd(&cnts[0], __popcll(m3));
                base3 = __shfl(base3, leader3, 64);
                pos = base3 + __popcll(m3 & ((1ULL << lane) - 1));
            }
        }
    }

    if (pos >= 0) {
        const float sv = nmsS[i];
        cS[pos]  = sv;
        cY1[pos] = pY1[i]; cX1[pos] = pX1[i];
        cY2[pos] = pY2[i]; cX2[pos] = pX2[i];
        if (sv > NEGV * 0.5f) atomicAdd(&cnts[2], 1);
    }
}

// ============================================================
// sort_k: 8-pass 4-bit LSD radix on key32 = ~m (asc = score desc).
// Stable by construction (thread-chunk order -> lane scan -> wave base),
// so the final permutation is identical to the old 64-bit (key,idx)
// bitonic sort. 6144 = 6 elems x 1024 threads; slots >= PRE_NMS carry
// sentinel key 0xFFFFFFFF and sort (stably) to the tail.
// ============================================================
__global__ __launch_bounds__(1024) void sort_k(
    const float* __restrict__ cS,
    const float* __restrict__ cY1, const float* __restrict__ cX1,
    const float* __restrict__ cY2, const float* __restrict__ cX2,
    float* __restrict__ sY1, float* __restrict__ sX1,
    float* __restrict__ sY2, float* __restrict__ sX2,
    float* __restrict__ sAr)
{
    __shared__ unsigned long long A[6144];
    __shared__ unsigned long long B[6144];
    __shared__ unsigned int wsum[16 * 16];   // [digit][wave] wave totals
    __shared__ unsigned int dtot[16];        // per-digit totals
    __shared__ unsigned int gb[16 * 16];     // [digit][wave] global bases
    const int t = threadIdx.x;
    const int w = t >> 6, lane = t & 63;

    for (int i = t; i < 6144; i += 1024) {
        unsigned long long k;
        if (i < PRE_NMS) {
            const unsigned bb = __float_as_uint(cS[i]);
            const unsigned m = (bb & 0x80000000u) ? ~bb : (bb | 0x80000000u);
            k = ((unsigned long long)(~m) << 32) | (unsigned)i;
        } else {
            k = 0xFFFFFFFF00000000ULL | (unsigned)i;
        }
        A[i] = k;
    }
    __syncthreads();

    unsigned long long* src = A;
    unsigned long long* dst = B;
    #pragma unroll 1
    for (int p = 0; p < 8; ++p) {
        const int sh = 32 + p * 4;
        const int b6 = t * 6;
        const unsigned long long e0 = src[b6+0], e1 = src[b6+1], e2 = src[b6+2],
                                 e3 = src[b6+3], e4 = src[b6+4], e5 = src[b6+5];
        const int d0 = (int)((e0 >> sh) & 15);
        const int d1 = (int)((e1 >> sh) & 15);
        const int d2 = (int)((e2 >> sh) & 15);
        const int d3 = (int)((e3 >> sh) & 15);
        const int d4 = (int)((e4 >> sh) & 15);
        const int d5 = (int)((e5 >> sh) & 15);
        // within-thread rank among earlier elements with the same digit
        const int r1 = (d1==d0);
        const int r2 = (d2==d0)+(d2==d1);
        const int r3 = (d3==d0)+(d3==d1)+(d3==d2);
        const int r4 = (d4==d0)+(d4==d1)+(d4==d2)+(d4==d3);
        const int r5 = (d5==d0)+(d5==d1)+(d5==d2)+(d5==d3)+(d5==d4);

        int exclv[16];   // only indexed by unrolled-constant v
        #pragma unroll
        for (int v = 0; v < 16; ++v) {
            const int c = (d0==v)+(d1==v)+(d2==v)+(d3==v)+(d4==v)+(d5==v);
            int s = c;
            #pragma unroll
            for (int o = 1; o < 64; o <<= 1) {
                const int u = __shfl_up(s, (unsigned)o, 64);
                if (lane >= o) s += u;
            }
            exclv[v] = s - c;                       // same-digit count in earlier lanes
            if (lane == 63) wsum[v * 16 + w] = (unsigned)s;
        }
        __syncthreads();
        if (t < 16) {
            unsigned s2 = 0;
            for (int w2 = 0; w2 < 16; ++w2) s2 += wsum[t * 16 + w2];
            dtot[t] = s2;
        }
        __syncthreads();
        if (t < 256) {
            const int v = t >> 4, ww = t & 15;
            unsigned bs = 0;
            for (int v2 = 0; v2 < v; ++v2) bs += dtot[v2];
            for (int w2 = 0; w2 < ww; ++w2) bs += wsum[v * 16 + w2];
            gb[t] = bs;
        }
        __syncthreads();
        #pragma unroll
        for (int v = 0; v < 16; ++v) {
            const int myb = (int)gb[v * 16 + w] + exclv[v];
            if (d0 == v) dst[myb]      = e0;
            if (d1 == v) dst[myb + r1] = e1;
            if (d2 == v) dst[myb + r2] = e2;
            if (d3 == v) dst[myb + r3] = e3;
            if (d4 == v) dst[myb + r4] = e4;
            if (d5 == v) dst[myb + r5] = e5;
        }
        __syncthreads();
        unsigned long long* tmp = src; src = dst; dst = tmp;
    }
    // 8 passes (even) -> sorted data back in A (== src)

    for (int i = t; i < NSORT; i += 1024) {
        if (i < PRE_NMS) {
            const int j = (int)(src[i] & 0xFFFFFFFFu);
            const float y1 = cY1[j], x1 = cX1[j], y2 = cY2[j], x2 = cX2[j];
            sY1[i] = y1; sX1[i] = x1; sY2[i] = y2; sX2[i] = x2;
            sAr[i] = (y2 - y1) * (x2 - x1);
        } else {
            sY1[i] = 0.f; sX1[i] = 0.f; sY2[i] = 0.f; sX2[i] = 0.f; sAr[i] = 0.f;
        }
    }
}

// ============================================================
// mask_k: suppression bitmask. mask[r*94+bj] bit u = iou(r, bj*64+u)>0.7
// ============================================================
__global__ __launch_bounds__(64) void mask_k(
    const float* __restrict__ sY1, const float* __restrict__ sX1,
    const float* __restrict__ sY2, const float* __restrict__ sX2,
    const float* __restrict__ sAr, unsigned long long* __restrict__ mask)
{
    __shared__ float ly1[64], lx1[64], ly2[64], lx2[64], lar[64];
    const int t = threadIdx.x;
    const int c = blockIdx.y * 64 + t;
    ly1[t] = sY1[c]; lx1[t] = sX1[c]; ly2[t] = sY2[c]; lx2[t] = sX2[c]; lar[t] = sAr[c];
    __syncthreads();
    const int r = blockIdx.x * 64 + t;
    const float ry1 = sY1[r], rx1 = sX1[r], ry2 = sY2[r], rx2 = sX2[r], rar = sAr[r];
    unsigned long long bits = 0ULL;
    #pragma unroll 8
    for (int u = 0; u < 64; ++u) {
        const float iy1 = fmaxf(ry1, ly1[u]);
        const float ix1 = fmaxf(rx1, lx1[u]);
        const float iy2 = fminf(ry2, ly2[u]);
        const float ix2 = fminf(rx2, lx2[u]);
        const float inter = fmaxf(iy2 - iy1, 0.f) * fmaxf(ix2 - ix1, 0.f);
        const float iou = inter / (lar[u] + rar - inter + 1e-8f);
        bits |= (iou > 0.7f) ? (1ULL << u) : 0ULL;
    }
    mask[(size_t)r * NWORDS + blockIdx.y] = bits;
}

// ============================================================
// scan2_k: greedy NMS scan, 4 waves + double-buffered mask staging.
// ============================================================
__global__ __launch_bounds__(256) void scan2_k(
    const float* __restrict__ sY1, const float* __restrict__ sX1,
    const float* __restrict__ sY2, const float* __restrict__ sX2,
    const unsigned long long* __restrict__ mask, const int* __restrict__ cnts,
    float* __restrict__ outP)
{
    __shared__ alignas(16) unsigned long long rows[2][64][96];
    __shared__ int sn;
    const int tid = threadIdx.x;
    const int wv = tid >> 6, l = tid & 63;
    const int nvRaw = cnts[2];
    const int nv = nvRaw < PRE_NMS ? nvRaw : PRE_NMS;
    const int nw = (nv + 63) >> 6;          // words of candidates (<= NWORDS)
    unsigned long long r0 = 0ULL, r1 = 0ULL;
    int n = 0;
    if (tid == 0) sn = 0;

    // wave wv stages rows [wv*16, wv*16+16) of a word: 16 GLL16 per wave
    #define SSTAGE(w_, buf_)                                                     \
        for (int r = 0; r < 16; ++r) {                                           \
            if (l < 47)                                                          \
                GLL16(mask + (size_t)(((w_) << 6) + wv * 16 + r) * NWORDS + 2*l, \
                      &rows[buf_][wv * 16 + r][0]);                              \
        }

    if (nw > 0) { SSTAGE(0, 0); }

    for (int w = 0; w < nw; ++w) {
        const int buf = w & 1;
        const bool pf = (w + 1 < nw);
        if (pf) {
            SSTAGE(w + 1, buf ^ 1);
            asm volatile("s_waitcnt vmcnt(16)" ::: "memory");   // drain word w only
        } else {
            asm volatile("s_waitcnt vmcnt(0)" ::: "memory");
        }
        __syncthreads();

        if (wv == 0) {
            const int base = w << 6;
            const int ci = base + l;
            const float v1 = sY1[ci], v2 = sX1[ci], v3 = sY2[ci], v4 = sX2[ci];
            unsigned long long cw = (w < 64) ? __shfl(r0, w, 64) : __shfl(r1, w - 64, 64);
            const int lim = nv - base;
            if (lim < 64) cw |= (~0ULL << lim);
            while (cw != ~0ULL && n < POST_NMS) {
                const int b = (int)__builtin_ctzll(~cw);
                const float by1 = __shfl(v1, b, 64);
                const float bx1 = __shfl(v2, b, 64);
                const float by2 = __shfl(v3, b, 64);
                const float bx2 = __shfl(v4, b, 64);
                if (l == 0) {
                    outP[4 * n + 0] = by1; outP[4 * n + 1] = bx1;
                    outP[4 * n + 2] = by2; outP[4 * n + 3] = bx2;
                }
                ++n;
                cw |= (1ULL << b);
                if (n >= POST_NMS) break;
                r0 |= rows[buf][b][l];
                if (l < NWORDS - 64) r1 |= rows[buf][b][64 + l];
                cw |= rows[buf][b][w];
            }
            if (l == 0) sn = n;
        }
        __syncthreads();
        n = sn;
        if (n >= POST_NMS) break;
    }
    #undef SSTAGE
    asm volatile("s_waitcnt vmcnt(0)" ::: "memory");   // drain stray prefetch

    for (int idx = 4 * n + tid; idx < 4 * POST_NMS; idx += 256) outP[idx] = 0.f;
}

// ============================================================
extern "C" void kernel_launch(void* const* d_in, const int* in_sizes, int n_in,
                              void* d_out, int out_size, void* d_ws, size_t ws_size,
                              hipStream_t stream)
{
    const float* X    = (const float*)d_in[1];
    const float* anch = (const float*)d_in[2];
    const float* W1   = (const float*)d_in[3];
    const float* b1   = (const float*)d_in[4];
    const float* Wc   = (const float*)d_in[5];
    const float* bc   = (const float*)d_in[6];
    const float* Wr   = (const float*)d_in[7];
    const float* br   = (const float*)d_in[8];

    float* out = (float*)d_out;
    float* ws  = (float*)d_ws;

    unsigned short* Yh = (unsigned short*)(ws + OYREG);
    unsigned short* Yl = Yh + (size_t)NPIX * CONV_C;
    unsigned short* Xh = (unsigned short*)(ws + OXH);
    unsigned short* Xl = (unsigned short*)(ws + OXL);
    unsigned short* Wh = (unsigned short*)(ws + OWH);
    unsigned short* Wl = (unsigned short*)(ws + OWL);
    float* rawS = ws + ORAW;
    float* nmsS = ws + ONMS;
    float* pY1  = ws + OPY1;
    float* pX1  = ws + OPX1;
    float* pY2  = ws + OPY2;
    float* pX2  = ws + OPX2;
    unsigned int* hist = (unsigned int*)(ws + OHIST);
    int* cnts   = (int*)(ws + OCNT);
    int* params = (int*)(ws + OPAR);
    float* cS   = ws + OCS;
    float* cY1  = ws + OCY1;
    float* cX1  = ws + OCX1;
    float* cY2  = ws + OCY2;
    float* cX2  = ws + OCX2;
    unsigned short* W2h = (unsigned short*)(ws + OW2H);
    unsigned short* W2l = (unsigned short*)(ws + OW2L);
    float* sY1  = ws + OSY1;
    float* sX1  = ws + OSX1;
    float* sY2  = ws + OSY2;
    float* sX2  = ws + OSX2;
    float* sAr  = ws + OSAR;
    unsigned long long* mask = (unsigned long long*)(ws + OMASK);

    float* out_scores = out;
    float* out_deltas = out + NBOX;
    float* out_props  = out + (size_t)NBOX * 5;

    hipMemsetAsync(hist, 0, (NHBINS + 8) * sizeof(unsigned int), stream);
    hipMemsetAsync(Xh, 0, 2 * NPAD * sizeof(unsigned short), stream);

    split_x<<<8000, 256, 0, stream>>>(X, Xh, Xl);
    split_w<<<576, 256, 0, stream>>>(W1, Wh, Wl);
    split_w2<<<96, 256, 0, stream>>>(Wc, Wr, W2h, W2l);

    conv_mfma<<<dim3(125, 4), 256, 0, stream>>>(Xh, Xl, Wh, Wl, b1, Yh, Yl);

    heads_mfma<<<125, 256, 0, stream>>>(Yh, Yl, W2h, W2l, bc, br, anch,
        out_scores, out_deltas, rawS, nmsS, pY1, pX1, pY2, pX2, hist);

    select_k<<<1, 1024, 0, stream>>>(hist, params);
    compact_k<<<(NBOX + 255) / 256, 256, 0, stream>>>(
        rawS, nmsS, pY1, pX1, pY2, pX2, params, cnts, cS, cY1, cX1, cY2, cX2);

    sort_k<<<1, 1024, 0, stream>>>(cS, cY1, cX1, cY2, cX2,
                                   sY1, sX1, sY2, sX2, sAr);
    mask_k<<<dim3(NWORDS, NWORDS), 64, 0, stream>>>(sY1, sX1, sY2, sX2, sAr, mask);
    scan2_k<<<1, 256, 0, stream>>>(sY1, sX1, sY2, sX2, mask, cnts, out_props);
}

// Round 8
// 629.682 us; speedup vs baseline: 1.0476x; 1.0476x over previous
//
#include <hip/hip_runtime.h>
#include <math.h>

#define HF 100
#define WFD 160
#define CIN 512
#define CONV_C 512
#define NPIX (HF*WFD)           // 16000
#define NBOX (NPIX*9)           // 144000
#define PRE_NMS 6000
#define POST_NMS 300
#define NEGV (-1.0e9f)
#define IMG_H 1600.0f
#define IMG_W 2560.0f
#define NHBINS 32768
#define NWORDS 94               // ceil(6000/64)
#define NSORT 6016              // 94*64

// padded X: 102 rows x 162 cols x 512 ch
#define PR 102
#define PC 162
#define NPAD ((size_t)PR*PC*512)   // 8,460,288 ushorts per array

// prep_k grid layout
#define PB_SX   8000                       // split_x blocks
#define PB_SW   576                        // split_w blocks
#define PB_SW2  96                         // split_w2 blocks
#define PB_HZ   32                         // hist-zero blocks
#define NBORD   524                        // border pixels (2*PC + 2*(PR-2))
#define PB_BZ   262                        // border-zero blocks: 524*64*2/256
#define PB_TOT  (PB_SX+PB_SW+PB_SW2+PB_HZ+PB_BZ)   // 8966

typedef __attribute__((ext_vector_type(8))) _Float16 half8;
typedef __attribute__((ext_vector_type(4))) float floatx4;

__device__ __forceinline__ unsigned short f2h_hi(float x) {
    _Float16 h = (_Float16)x;
    return __builtin_bit_cast(unsigned short, h);
}
__device__ __forceinline__ unsigned short f2h_lo(float x, unsigned short hbits) {
    _Float16 h = __builtin_bit_cast(_Float16, hbits);
    _Float16 l = (_Float16)((x - (float)h) * 2048.0f);   // scaled residual: stays normal
    return __builtin_bit_cast(unsigned short, l);
}

#define GLL16(g, l) __builtin_amdgcn_global_load_lds( \
    (const __attribute__((address_space(1))) void*)(g), \
    (__attribute__((address_space(3))) void*)(l), 16, 0, 0)

// ---- workspace layout (units: floats) ----
static const size_t OYREG = 0;
static const size_t OXH   = OYREG + (size_t)NPIX * CONV_C;  // Xh ushorts; dead after conv
static const size_t OXL   = OXH + NPAD / 2;                 // Xl ushorts; dead after conv
static const size_t OWH   = OXL + NPAD / 2;                 // fp16 [9][n=512][k=512]
static const size_t OWL   = OWH + (size_t)9*512*512/2;
static const size_t ORAW  = OWL + (size_t)9*512*512/2;
static const size_t ONMS  = ORAW + NBOX;
static const size_t OPY1  = ONMS + NBOX;
static const size_t OPX1  = OPY1 + NBOX;
static const size_t OPY2  = OPX1 + NBOX;
static const size_t OPX2  = OPY2 + NBOX;
static const size_t OHIST = OPX2 + NBOX;                    // 32768 uints
static const size_t OCNT  = OHIST + NHBINS;                 // 4 ints
static const size_t OPAR  = OCNT + 4;                       // 2 ints
static const size_t OCS   = OPAR + 2;                       // 6000
static const size_t OCY1  = OCS + PRE_NMS;
static const size_t OCX1  = OCY1 + PRE_NMS;
static const size_t OCY2  = OCX1 + PRE_NMS;
static const size_t OCX2  = OCY2 + PRE_NMS;
static const size_t OW2H  = OCX2 + PRE_NMS;                 // 48*512 ushorts = 12288 floats
static const size_t OW2L  = OW2H + 12288;
// overlays (written after conv_mfma is done):
static const size_t OMASK = OXH;                            // u64[6016*94]
static const size_t OSY1  = OXL;                            // 6016 each, 5 arrays
static const size_t OSX1  = OSY1 + NSORT;
static const size_t OSY2  = OSX1 + NSORT;
static const size_t OSX2  = OSY2 + NSORT;
static const size_t OSAR  = OSX2 + NSORT;

// ============================================================
// prep_k: fused preprocessing — one launch replaces
//   memset(hist)+memset(Xh/Xl)+split_x+split_w+split_w2.
// Block ranges:
//   [0,8000)        split_x  (interior pixels -> no overlap with border)
//   [8000,8576)     split_w
//   [8576,8672)     split_w2
//   [8672,8704)     zero hist+cnts+params (32776 uints)
//   [8704,8966)     zero the 524-pixel pad border of Xh/Xl (uint4 stores)
// All sub-bodies are the r3/r7-verified code, only reindexed.
// ============================================================
__global__ __launch_bounds__(256) void prep_k(
    const float* __restrict__ X, const float* __restrict__ W1,
    const float* __restrict__ Wc, const float* __restrict__ Wr,
    unsigned short* __restrict__ Xh, unsigned short* __restrict__ Xl,
    unsigned short* __restrict__ Wh, unsigned short* __restrict__ Wl,
    unsigned short* __restrict__ W2h, unsigned short* __restrict__ W2l,
    unsigned int* __restrict__ hist)
{
    __shared__ unsigned short Lh[64 * 64];
    __shared__ unsigned short Ll[64 * 64];
    const int B = blockIdx.x;
    const int t = threadIdx.x;

    if (B < PB_SX) {
        // ---- split_x ----
        const int idx = B * 256 + t;
        const int p = idx >> 7;
        const int kq = (idx & 127) * 4;
        const float4 v = *(const float4*)(X + (size_t)p * 512 + kq);
        const int r = p / WFD, c = p % WFD;
        const size_t dst = ((size_t)(r + 1) * PC + (c + 1)) * 512 + kq;
        float vv[4] = { v.x, v.y, v.z, v.w };
        unsigned short h[4], lo[4];
        #pragma unroll
        for (int u = 0; u < 4; ++u) {
            h[u]  = f2h_hi(vv[u]);
            lo[u] = f2h_lo(vv[u], h[u]);
        }
        uint2 ph, pl;
        ph.x = (unsigned)h[0]  | ((unsigned)h[1]  << 16);
        ph.y = (unsigned)h[2]  | ((unsigned)h[3]  << 16);
        pl.x = (unsigned)lo[0] | ((unsigned)lo[1] << 16);
        pl.y = (unsigned)lo[2] | ((unsigned)lo[3] << 16);
        *(uint2*)(Xh + dst) = ph;
        *(uint2*)(Xl + dst) = pl;
    } else if (B < PB_SX + PB_SW) {
        // ---- split_w ----
        const int blk = B - PB_SX;
        const int dydx = blk >> 6;
        const int rem  = blk & 63;
        const int k0 = (rem >> 3) * 64, n0 = (rem & 7) * 64;
        #pragma unroll
        for (int i = 0; i < 4; ++i) {
            const int f = t + 256 * i;
            const int row = f >> 4;
            const int cp  = (f & 15) * 4;
            const float4 v = *(const float4*)(W1 + ((size_t)(dydx * 512 + k0 + row)) * 512 + n0 + cp);
            float vv[4] = { v.x, v.y, v.z, v.w };
            #pragma unroll
            for (int u = 0; u < 4; ++u) {
                const unsigned short h = f2h_hi(vv[u]);
                Lh[(cp + u) * 64 + row] = h;
                Ll[(cp + u) * 64 + row] = f2h_lo(vv[u], h);
            }
        }
        __syncthreads();
        const int n  = t >> 2;
        const int kp = (t & 3) * 16;
        const size_t gbase = ((size_t)(dydx * 512 + n0 + n)) * 512 + k0 + kp;
        *(uint4*)(Wh + gbase)     = *(const uint4*)(Lh + n * 64 + kp);
        *(uint4*)(Wh + gbase + 8) = *(const uint4*)(Lh + n * 64 + kp + 8);
        *(uint4*)(Wl + gbase)     = *(const uint4*)(Ll + n * 64 + kp);
        *(uint4*)(Wl + gbase + 8) = *(const uint4*)(Ll + n * 64 + kp + 8);
    } else if (B < PB_SX + PB_SW + PB_SW2) {
        // ---- split_w2 ----
        const int i = (B - PB_SX - PB_SW) * 256 + t;   // 0..24575
        if (i < 48 * 512) {
            const int n = i >> 9, k = i & 511;
            float v = 0.f;
            if (n < 9) v = Wc[k * 9 + n];
            else if (n < 45) v = Wr[k * 36 + (n - 9)];
            const unsigned short h = f2h_hi(v);
            W2h[i] = h;
            W2l[i] = f2h_lo(v, h);
        }
    } else if (B < PB_SX + PB_SW + PB_SW2 + PB_HZ) {
        // ---- zero hist + cnts + params (matches old memset of NHBINS+8) ----
        for (int i = (B - PB_SX - PB_SW - PB_SW2) * 256 + t; i < NHBINS + 8; i += PB_HZ * 256)
            hist[i] = 0u;
    } else {
        // ---- zero pad border of Xh/Xl: 524 pixels x 64 uint4-chunks x 2 arrays ----
        const int s = (B - PB_SX - PB_SW - PB_SW2 - PB_HZ) * 256 + t;
        if (s < NBORD * 64 * 2) {
            const int arr = (s >= NBORD * 64) ? 1 : 0;
            const int si  = arr ? s - NBORD * 64 : s;
            const int pix = si >> 6, chunk = si & 63;
            int r, c;
            if (pix < PC)            { r = 0;                      c = pix; }
            else if (pix < 2 * PC)   { r = PR - 1;                 c = pix - PC; }
            else if (pix < 2 * PC + (PR - 2)) { r = 1 + (pix - 2 * PC);            c = 0; }
            else                     { r = 1 + (pix - 2 * PC - (PR - 2)); c = PC - 1; }
            unsigned short* dstA = arr ? Xl : Xh;
            uint4 z; z.x = 0u; z.y = 0u; z.z = 0u; z.w = 0u;
            *(uint4*)(dstA + ((size_t)r * PC + c) * 512 + chunk * 8) = z;
        }
    }
}

// ============================================================
// conv 3x3 512->512, split-fp16 3-pass MFMA.
// r2/r3/r7-VERIFIED structure: XOR chunk swizzle keeps staging coalesced
// AND ds_read conflict-free; double-buffered with counted vmcnt(8);
// two barriers per K-step.
// ============================================================
__global__ __launch_bounds__(256, 2) void conv_mfma(
    const unsigned short* __restrict__ Xh, const unsigned short* __restrict__ Xl,
    const unsigned short* __restrict__ Wh, const unsigned short* __restrict__ Wl,
    const float* __restrict__ b1,
    unsigned short* __restrict__ Yh, unsigned short* __restrict__ Yl)
{
    __shared__ alignas(16) unsigned short Ah[2][128 * 32];
    __shared__ alignas(16) unsigned short Al[2][128 * 32];
    __shared__ alignas(16) unsigned short Bh[2][128 * 32];
    __shared__ alignas(16) unsigned short Bl[2][128 * 32];

    const int tid = threadIdx.x;
    const int w = tid >> 6, l = tid & 63;
    const int wy = w >> 1, wx = w & 1;

    const int bx = blockIdx.x;
    const int q = bx & 7, s5 = bx >> 3;
    const int tile = (q < 5) ? (q * 16 + s5) : (80 + (q - 5) * 15 + s5);
    const int pm0 = tile * 128, oc0 = blockIdx.y * 128;

    // staging offsets: row = l>>2 (coalesced), chunk XOR-swizzled in-line
    const int swW = ((l & 3) ^ ((l >> 3) & 3)) * 8;   // write-side chunk (ushorts)
    int aoff[2], boff[2], ldsOff[2];
    #pragma unroll
    for (int i = 0; i < 2; ++i) {
        const int m = w * 32 + i * 16 + (l >> 2);
        const int p = pm0 + m;
        const int r = p / WFD, c = p % WFD;
        aoff[i] = ((r + 1) * PC + (c + 1)) * 512 + swW;
        boff[i] = (oc0 + m) * 512 + swW;
        ldsOff[i] = (w * 32 + i * 16) * 32;
    }

    // fragment read offsets: row_in_region = l&15, chunk = (l>>4)^((l>>1)&3)
    const int swR = (((l >> 4) ^ ((l >> 1) & 3))) * 8;
    int afrag[4], bfrag[4];
    #pragma unroll
    for (int i = 0; i < 4; ++i) {
        afrag[i] = (wy * 64 + i * 16 + (l & 15)) * 32 + swR;
        bfrag[i] = (wx * 64 + i * 16 + (l & 15)) * 32 + swR;
    }

    floatx4 acc[4][4], accL[4][4];
    #pragma unroll
    for (int j = 0; j < 4; ++j) {
        const float bv = b1[oc0 + wx * 64 + j * 16 + (l & 15)];
        #pragma unroll
        for (int i = 0; i < 4; ++i) {
            acc[i][j][0] = bv; acc[i][j][1] = bv; acc[i][j][2] = bv; acc[i][j][3] = bv;
            accL[i][j][0] = 0.f; accL[i][j][1] = 0.f; accL[i][j][2] = 0.f; accL[i][j][3] = 0.f;
        }
    }

    #define CSTAGE(bf, dAx, dBx)                                    \
        _Pragma("unroll")                                           \
        for (int i = 0; i < 2; ++i) {                               \
            GLL16(Xh + aoff[i] + (dAx), Ah[bf] + ldsOff[i]);        \
            GLL16(Xl + aoff[i] + (dAx), Al[bf] + ldsOff[i]);        \
            GLL16(Wh + boff[i] + (dBx), Bh[bf] + ldsOff[i]);        \
            GLL16(Wl + boff[i] + (dBx), Bl[bf] + ldsOff[i]);        \
        }

    // prologue: stage step 0 (dydx=0 -> dy=-1,dx=-1; k0=0) into buffer 0
    CSTAGE(0, (-PC - 1) * 512, 0);

    for (int step = 0; step < 144; ++step) {
        const int cur = step & 1;
        if (step < 143) {
            const int s1 = step + 1;
            const int d1 = s1 >> 4;
            const int k1 = (s1 & 15) << 5;
            const int dy = d1 / 3 - 1, dx = d1 % 3 - 1;
            CSTAGE(cur ^ 1, (dy * PC + dx) * 512 + k1, d1 * (512 * 512) + k1);
            asm volatile("s_waitcnt vmcnt(8)" ::: "memory");
        } else {
            asm volatile("s_waitcnt vmcnt(0)" ::: "memory");
        }
        __builtin_amdgcn_s_barrier();
        asm volatile("" ::: "memory");

        const unsigned short* Ac = Ah[cur];
        const unsigned short* Lc = Al[cur];
        const unsigned short* Bc = Bh[cur];
        const unsigned short* Mc = Bl[cur];
        half8 fah[4], fal[4], fbh[4], fbl[4];
        #pragma unroll
        for (int i = 0; i < 4; ++i) {
            fah[i] = *(const half8*)(Ac + afrag[i]);
            fal[i] = *(const half8*)(Lc + afrag[i]);
            fbh[i] = *(const half8*)(Bc + bfrag[i]);
            fbl[i] = *(const half8*)(Mc + bfrag[i]);
        }
        #pragma unroll
        for (int i = 0; i < 4; ++i)
            #pragma unroll
            for (int j = 0; j < 4; ++j) {
                acc[i][j]  = __builtin_amdgcn_mfma_f32_16x16x32_f16(fah[i], fbh[j], acc[i][j], 0, 0, 0);
                accL[i][j] = __builtin_amdgcn_mfma_f32_16x16x32_f16(fal[i], fbh[j], accL[i][j], 0, 0, 0);
                accL[i][j] = __builtin_amdgcn_mfma_f32_16x16x32_f16(fah[i], fbl[j], accL[i][j], 0, 0, 0);
            }
        asm volatile("" ::: "memory");
        __builtin_amdgcn_s_barrier();
    }
    #undef CSTAGE

    // epilogue: ReLU + fp16 hi/lo split + store
    #pragma unroll
    for (int i = 0; i < 4; ++i) {
        const int row0 = pm0 + wy * 64 + i * 16 + (l >> 4) * 4;
        #pragma unroll
        for (int j = 0; j < 4; ++j) {
            const int col = oc0 + wx * 64 + j * 16 + (l & 15);
            #pragma unroll
            for (int r = 0; r < 4; ++r) {
                const float yv = fmaxf(acc[i][j][r] + accL[i][j][r] * 4.8828125e-4f, 0.f);
                const unsigned short h = f2h_hi(yv);
                const size_t o = (size_t)(row0 + r) * 512 + col;
                Yh[o] = h;
                Yl[o] = f2h_lo(yv, h);
            }
        }
    }
}

// ============================================================
// heads as skinny split-fp16 MFMA GEMM (r3-verified, LDS histogram).
// ============================================================
__global__ __launch_bounds__(256) void heads_mfma(
    const unsigned short* __restrict__ Yh, const unsigned short* __restrict__ Yl,
    const unsigned short* __restrict__ W2h, const unsigned short* __restrict__ W2l,
    const float* __restrict__ bc, const float* __restrict__ br,
    const float* __restrict__ anch,
    float* __restrict__ out_scores, float* __restrict__ out_deltas,
    float* __restrict__ rawS, float* __restrict__ nmsS,
    float* __restrict__ pY1, float* __restrict__ pX1,
    float* __restrict__ pY2, float* __restrict__ pX2,
    unsigned int* __restrict__ hist)
{
    __shared__ alignas(16) unsigned short Ah[128 * 32];
    __shared__ alignas(16) unsigned short Al[128 * 32];
    __shared__ alignas(16) unsigned short Bh[48 * 32];
    __shared__ alignas(16) unsigned short Bl[48 * 32];
    __shared__ float Lg[128 * 49];
    __shared__ unsigned int Hh[NHBINS / 2];   // packed u16-pair histogram, 64KB

    const int tid = threadIdx.x;
    const int w = tid >> 6, l = tid & 63;
    const int pm0 = blockIdx.x * 128;

    // zero the LDS histogram (covered by the first k-loop __syncthreads)
    #pragma unroll 4
    for (int i = tid; i < NHBINS / 2; i += 256) Hh[i] = 0u;

    const int swW = ((l & 3) ^ ((l >> 3) & 3)) * 8;
    int aoff[2], ldsOff[2];
    #pragma unroll
    for (int i = 0; i < 2; ++i) {
        const int m = w * 32 + i * 16 + (l >> 2);
        aoff[i] = (pm0 + m) * 512 + swW;
        ldsOff[i] = (w * 32 + i * 16) * 32;
    }
    // B staging: waves 0..2 each cover 16 weight rows
    const int bglb = (w * 16 + (l >> 2)) * 512 + swW;  // valid for w<3
    const int blds = w * 16 * 32;

    const int swR = (((l >> 4) ^ ((l >> 1) & 3))) * 8;
    int afrag[2], bfrag[3];
    #pragma unroll
    for (int i = 0; i < 2; ++i)
        afrag[i] = (w * 32 + i * 16 + (l & 15)) * 32 + swR;
    #pragma unroll
    for (int j = 0; j < 3; ++j)
        bfrag[j] = (j * 16 + (l & 15)) * 32 + swR;

    floatx4 acc[2][3], accL[2][3];
    #pragma unroll
    for (int i = 0; i < 2; ++i)
        #pragma unroll
        for (int j = 0; j < 3; ++j) {
            acc[i][j][0] = 0.f; acc[i][j][1] = 0.f; acc[i][j][2] = 0.f; acc[i][j][3] = 0.f;
            accL[i][j] = acc[i][j];
        }

    for (int k0 = 0; k0 < 512; k0 += 32) {
        __syncthreads();
        #pragma unroll
        for (int i = 0; i < 2; ++i) {
            GLL16(Yh + aoff[i] + k0, Ah + ldsOff[i]);
            GLL16(Yl + aoff[i] + k0, Al + ldsOff[i]);
        }
        if (w < 3) {
            GLL16(W2h + bglb + k0, Bh + blds);
            GLL16(W2l + bglb + k0, Bl + blds);
        }
        __syncthreads();
        half8 fah[2], fal[2], fbh[3], fbl[3];
        #pragma unroll
        for (int i = 0; i < 2; ++i) {
            fah[i] = *(const half8*)(Ah + afrag[i]);
            fal[i] = *(const half8*)(Al + afrag[i]);
        }
        #pragma unroll
        for (int j = 0; j < 3; ++j) {
            fbh[j] = *(const half8*)(Bh + bfrag[j]);
            fbl[j] = *(const half8*)(Bl + bfrag[j]);
        }
        #pragma unroll
        for (int i = 0; i < 2; ++i)
            #pragma unroll
            for (int j = 0; j < 3; ++j) {
                acc[i][j]  = __builtin_amdgcn_mfma_f32_16x16x32_f16(fah[i], fbh[j], acc[i][j], 0, 0, 0);
                accL[i][j] = __builtin_amdgcn_mfma_f32_16x16x32_f16(fal[i], fbh[j], accL[i][j], 0, 0, 0);
                accL[i][j] = __builtin_amdgcn_mfma_f32_16x16x32_f16(fah[i], fbl[j], accL[i][j], 0, 0, 0);
            }
    }

    // logits -> LDS. C/D: col=lane&15, row=(lane>>4)*4+reg
    __syncthreads();
    #pragma unroll
    for (int i = 0; i < 2; ++i) {
        const int prow0 = w * 32 + i * 16 + (l >> 4) * 4;
        #pragma unroll
        for (int j = 0; j < 3; ++j) {
            const int col = j * 16 + (l & 15);
            #pragma unroll
            for (int r = 0; r < 4; ++r)
                Lg[(prow0 + r) * 49 + col] = acc[i][j][r] + accL[i][j][r] * 4.8828125e-4f;
        }
    }
    __syncthreads();

    if (tid < 128) {
        const int p = pm0 + tid;
        float ac[9], arr[36];
        #pragma unroll
        for (int a = 0; a < 9; ++a) ac[a] = Lg[tid * 49 + a] + bc[a];
        #pragma unroll
        for (int j = 0; j < 36; ++j) arr[j] = Lg[tid * 49 + 9 + j] + br[j];

        float m = ac[0];
        #pragma unroll
        for (int a = 1; a < 9; ++a) m = fmaxf(m, ac[a]);
        float s = 0.f, e[9];
        #pragma unroll
        for (int a = 0; a < 9; ++a) { e[a] = expf(ac[a] - m); s += e[a]; }
        #pragma unroll
        for (int a = 0; a < 9; ++a) e[a] = e[a] / s;

        #pragma unroll
        for (int a = 0; a < 9; ++a) out_scores[p * 9 + a] = e[a];
        #pragma unroll
        for (int a = 0; a < 9; ++a)
            *(float4*)(out_deltas + (size_t)p * 36 + 4 * a) =
                make_float4(arr[4*a], arr[4*a+1], arr[4*a+2], arr[4*a+3]);

        #pragma unroll
        for (int a = 0; a < 9; ++a) {
            const float4 an = *(const float4*)(anch + (size_t)p * 36 + 4 * a);
            const float cty = an.x + arr[4*a]   * an.z;
            const float ctx = an.y + arr[4*a+1] * an.w;
            const float szy = an.z * expf(arr[4*a+2]);
            const float szx = an.w * expf(arr[4*a+3]);
            float y1 = fmaxf(cty - 0.5f * szy, 0.f);
            float x1 = fmaxf(ctx - 0.5f * szx, 0.f);
            float y2 = fminf(cty + 0.5f * szy, IMG_H);
            float x2 = fminf(ctx + 0.5f * szx, IMG_W);
            const bool valid = ((y2 - y1) >= 16.f) && ((x2 - x1) >= 16.f);
            const int idx = p * 9 + a;
            rawS[idx] = e[a];
            nmsS[idx] = valid ? e[a] : NEGV;
            pY1[idx] = y1; pX1[idx] = x1; pY2[idx] = y2; pX2[idx] = x2;
            const unsigned b = __float_as_uint(e[a]) >> 15;
            atomicAdd(&Hh[b >> 1], (b & 1) ? 65536u : 1u);
        }
    }

    // flush LDS histogram to global (few hundred nonzero bins per block)
    __syncthreads();
    for (int i = tid; i < NHBINS / 2; i += 256) {
        const unsigned v = Hh[i];
        if (v) {
            const unsigned lo = v & 0xFFFFu;
            const unsigned hi = v >> 16;
            if (lo) atomicAdd(&hist[2 * i],     lo);
            if (hi) atomicAdd(&hist[2 * i + 1], hi);
        }
    }
}

// ============================================================
// select_k: parallel suffix-scan over histogram
// ============================================================
__global__ __launch_bounds__(1024) void select_k(const unsigned int* __restrict__ hist,
                                                 int* __restrict__ params)
{
    __shared__ unsigned int ps[1024];
    const int t = threadIdx.x;
    unsigned int loc[32];
    unsigned int sum = 0;
    #pragma unroll 4
    for (int i = 0; i < 32; ++i) { loc[i] = hist[t * 32 + i]; sum += loc[i]; }
    ps[t] = sum;
    for (int off = 1; off < 1024; off <<= 1) {
        __syncthreads();
        const unsigned int add = (t + off < 1024) ? ps[t + off] : 0u;
        __syncthreads();
        ps[t] += add;
    }
    __syncthreads();
    const unsigned int above = (t < 1023) ? ps[t + 1] : 0u;
    if (above < (unsigned)PRE_NMS && ps[t] >= (unsigned)PRE_NMS) {
        unsigned int cum = above;
        for (int j = 31; j >= 0; --j) {
            const unsigned int h = loc[j];
            if (cum + h >= (unsigned)PRE_NMS) {
                params[0] = t * 32 + j;
                params[1] = PRE_NMS - (int)cum;
                break;
            }
            cum += h;
        }
    }
}

// ============================================================
// compact_k (r3-verified simple version)
// ============================================================
__global__ void compact_k(const float* __restrict__ rawS, const float* __restrict__ nmsS,
                          const float* __restrict__ pY1, const float* __restrict__ pX1,
                          const float* __restrict__ pY2, const float* __restrict__ pX2,
                          const int* __restrict__ params, int* __restrict__ cnts,
                          float* __restrict__ cS,
                          float* __restrict__ cY1, float* __restrict__ cX1,
                          float* __restrict__ cY2, float* __restrict__ cX2)
{
    const int i = blockIdx.x * 256 + threadIdx.x;
    if (i >= NBOX) return;
    const int b = (int)(__float_as_uint(rawS[i]) >> 15);
    const int bin = params[0];
    const int need = params[1];
    int pos = -1;
    if (b > bin) {
        pos = atomicAdd(&cnts[0], 1);
    } else if (b == bin) {
        const int t2 = atomicAdd(&cnts[1], 1);
        if (t2 < need) pos = atomicAdd(&cnts[0], 1);
    }
    if (pos >= 0) {
        const float sv = nmsS[i];
        cS[pos]  = sv;
        cY1[pos] = pY1[i]; cX1[pos] = pX1[i];
        cY2[pos] = pY2[i]; cX2[pos] = pX2[i];
        if (sv > NEGV * 0.5f) atomicAdd(&cnts[2], 1);
    }
}

// ============================================================
// sort_k (r3-verified bitonic): sort by score desc, gather SoA boxes
// ============================================================
__global__ __launch_bounds__(1024) void sort_k(
    const float* __restrict__ cS,
    const float* __restrict__ cY1, const float* __restrict__ cX1,
    const float* __restrict__ cY2, const float* __restrict__ cX2,
    float* __restrict__ sY1, float* __restrict__ sX1,
    float* __restrict__ sY2, float* __restrict__ sX2,
    float* __restrict__ sAr)
{
    __shared__ unsigned long long keys[8192];
    const int t = threadIdx.x;
    for (int i = t; i < 8192; i += 1024) {
        unsigned long long k;
        if (i < PRE_NMS) {
            const unsigned b = __float_as_uint(cS[i]);
            const unsigned m = (b & 0x80000000u) ? ~b : (b | 0x80000000u);
            k = ((unsigned long long)(~m) << 32) | (unsigned)i;
        } else {
            k = ~0ULL;
        }
        keys[i] = k;
    }
    for (int kk = 2; kk <= 8192; kk <<= 1) {
        for (int j = kk >> 1; j > 0; j >>= 1) {
            __syncthreads();
            for (int t4 = t; t4 < 4096; t4 += 1024) {
                const int i  = ((t4 & ~(j - 1)) << 1) | (t4 & (j - 1));
                const int p2 = i | j;
                const bool up = ((i & kk) == 0);
                const unsigned long long a = keys[i], b = keys[p2];
                const bool sw = up ? (a > b) : (a < b);
                if (sw) { keys[i] = b; keys[p2] = a; }
            }
        }
    }
    __syncthreads();
    for (int i = t; i < NSORT; i += 1024) {
        if (i < PRE_NMS) {
            const int j = (int)(keys[i] & 0xFFFFFFFFu);
            const float y1 = cY1[j], x1 = cX1[j], y2 = cY2[j], x2 = cX2[j];
            sY1[i] = y1; sX1[i] = x1; sY2[i] = y2; sX2[i] = x2;
            sAr[i] = (y2 - y1) * (x2 - x1);
        } else {
            sY1[i] = 0.f; sX1[i] = 0.f; sY2[i] = 0.f; sX2[i] = 0.f; sAr[i] = 0.f;
        }
    }
}

// ============================================================
// mask_k: suppression bitmask. mask[r*94+bj] bit u = iou(r, bj*64+u)>0.7
// ============================================================
__global__ __launch_bounds__(64) void mask_k(
    const float* __restrict__ sY1, const float* __restrict__ sX1,
    const float* __restrict__ sY2, const float* __restrict__ sX2,
    const float* __restrict__ sAr, unsigned long long* __restrict__ mask)
{
    __shared__ float ly1[64], lx1[64], ly2[64], lx2[64], lar[64];
    const int t = threadIdx.x;
    const int c = blockIdx.y * 64 + t;
    ly1[t] = sY1[c]; lx1[t] = sX1[c]; ly2[t] = sY2[c]; lx2[t] = sX2[c]; lar[t] = sAr[c];
    __syncthreads();
    const int r = blockIdx.x * 64 + t;
    const float ry1 = sY1[r], rx1 = sX1[r], ry2 = sY2[r], rx2 = sX2[r], rar = sAr[r];
    unsigned long long bits = 0ULL;
    #pragma unroll 8
    for (int u = 0; u < 64; ++u) {
        const float iy1 = fmaxf(ry1, ly1[u]);
        const float ix1 = fmaxf(rx1, lx1[u]);
        const float iy2 = fminf(ry2, ly2[u]);
        const float ix2 = fminf(rx2, lx2[u]);
        const float inter = fmaxf(iy2 - iy1, 0.f) * fmaxf(ix2 - ix1, 0.f);
        const float iou = inter / (lar[u] + rar - inter + 1e-8f);
        bits |= (iou > 0.7f) ? (1ULL << u) : 0ULL;
    }
    mask[(size_t)r * NWORDS + blockIdx.y] = bits;
}

// ============================================================
// scan2_k (r3-verified): chunked-LDS greedy scan, one wave
// ============================================================
__global__ __launch_bounds__(64) void scan2_k(
    const float* __restrict__ sY1, const float* __restrict__ sX1,
    const float* __restrict__ sY2, const float* __restrict__ sX2,
    const unsigned long long* __restrict__ mask, const int* __restrict__ cnts,
    float* __restrict__ outP)
{
    __shared__ alignas(16) unsigned long long rows[64][96];
    const int l = threadIdx.x;
    const int nvRaw = cnts[2];
    const int nv = nvRaw < PRE_NMS ? nvRaw : PRE_NMS;
    unsigned long long r0 = 0ULL, r1 = 0ULL;
    int n = 0;
    for (int w = 0; w < NWORDS; ++w) {
        const int base = w << 6;
        if (base >= nv || n >= POST_NMS) break;
        for (int r = 0; r < 64; ++r) {
            if (l < 47)
                GLL16(mask + (size_t)(base + r) * NWORDS + 2 * l, &rows[r][0]);
        }
        const int ci = base + l;
        const float v1 = sY1[ci], v2 = sX1[ci], v3 = sY2[ci], v4 = sX2[ci];
        __syncthreads();
        unsigned long long cw = (w < 64) ? __shfl(r0, w, 64) : __shfl(r1, w - 64, 64);
        const int lim = nv - base;
        if (lim < 64) cw |= (~0ULL << lim);
        while (cw != ~0ULL && n < POST_NMS) {
            const int b = (int)__builtin_ctzll(~cw);
            const float by1 = __shfl(v1, b, 64);
            const float bx1 = __shfl(v2, b, 64);
            const float by2 = __shfl(v3, b, 64);
            const float bx2 = __shfl(v4, b, 64);
            if (l == 0) {
                outP[4 * n + 0] = by1; outP[4 * n + 1] = bx1;
                outP[4 * n + 2] = by2; outP[4 * n + 3] = bx2;
            }
            ++n;
            cw |= (1ULL << b);
            if (n >= POST_NMS) break;
            r0 |= rows[b][l];
            if (l < NWORDS - 64) r1 |= rows[b][64 + l];
            cw |= rows[b][w];
        }
        __syncthreads();
    }
    for (int idx = 4 * n + l; idx < 4 * POST_NMS; idx += 64) outP[idx] = 0.f;
}

// ============================================================
extern "C" void kernel_launch(void* const* d_in, const int* in_sizes, int n_in,
                              void* d_out, int out_size, void* d_ws, size_t ws_size,
                              hipStream_t stream)
{
    const float* X    = (const float*)d_in[1];
    const float* anch = (const float*)d_in[2];
    const float* W1   = (const float*)d_in[3];
    const float* b1   = (const float*)d_in[4];
    const float* Wc   = (const float*)d_in[5];
    const float* bc   = (const float*)d_in[6];
    const float* Wr   = (const float*)d_in[7];
    const float* br   = (const float*)d_in[8];

    float* out = (float*)d_out;
    float* ws  = (float*)d_ws;

    unsigned short* Yh = (unsigned short*)(ws + OYREG);
    unsigned short* Yl = Yh + (size_t)NPIX * CONV_C;
    unsigned short* Xh = (unsigned short*)(ws + OXH);
    unsigned short* Xl = (unsigned short*)(ws + OXL);
    unsigned short* Wh = (unsigned short*)(ws + OWH);
    unsigned short* Wl = (unsigned short*)(ws + OWL);
    float* rawS = ws + ORAW;
    float* nmsS = ws + ONMS;
    float* pY1  = ws + OPY1;
    float* pX1  = ws + OPX1;
    float* pY2  = ws + OPY2;
    float* pX2  = ws + OPX2;
    unsigned int* hist = (unsigned int*)(ws + OHIST);
    int* cnts   = (int*)(ws + OCNT);
    int* params = (int*)(ws + OPAR);
    float* cS   = ws + OCS;
    float* cY1  = ws + OCY1;
    float* cX1  = ws + OCX1;
    float* cY2  = ws + OCY2;
    float* cX2  = ws + OCX2;
    unsigned short* W2h = (unsigned short*)(ws + OW2H);
    unsigned short* W2l = (unsigned short*)(ws + OW2L);
    float* sY1  = ws + OSY1;
    float* sX1  = ws + OSX1;
    float* sY2  = ws + OSY2;
    float* sX2  = ws + OSX2;
    float* sAr  = ws + OSAR;
    unsigned long long* mask = (unsigned long long*)(ws + OMASK);

    float* out_scores = out;
    float* out_deltas = out + NBOX;
    float* out_props  = out + (size_t)NBOX * 5;

    // one fused prep launch: splits + hist/cnts zero + pad-border zero
    prep_k<<<PB_TOT, 256, 0, stream>>>(X, W1, Wc, Wr,
                                       Xh, Xl, Wh, Wl, W2h, W2l, hist);

    conv_mfma<<<dim3(125, 4), 256, 0, stream>>>(Xh, Xl, Wh, Wl, b1, Yh, Yl);

    heads_mfma<<<125, 256, 0, stream>>>(Yh, Yl, W2h, W2l, bc, br, anch,
        out_scores, out_deltas, rawS, nmsS, pY1, pX1, pY2, pX2, hist);

    select_k<<<1, 1024, 0, stream>>>(hist, params);
    compact_k<<<(NBOX + 255) / 256, 256, 0, stream>>>(
        rawS, nmsS, pY1, pX1, pY2, pX2, params, cnts, cS, cY1, cX1, cY2, cX2);

    sort_k<<<1, 1024, 0, stream>>>(cS, cY1, cX1, cY2, cX2,
                                   sY1, sX1, sY2, sX2, sAr);
    mask_k<<<dim3(NWORDS, NWORDS), 64, 0, stream>>>(sY1, sX1, sY2, sX2, sAr, mask);
    scan2_k<<<1, 64, 0, stream>>>(sY1, sX1, sY2, sX2, mask, cnts, out_props);
}

// Round 10
// 618.848 us; speedup vs baseline: 1.0660x; 1.0175x over previous
//
#include <hip/hip_runtime.h>
#include <math.h>

#define HF 100
#define WFD 160
#define CIN 512
#define CONV_C 512
#define NPIX (HF*WFD)           // 16000
#define NBOX (NPIX*9)           // 144000
#define PRE_NMS 6000
#define POST_NMS 300
#define NEGV (-1.0e9f)
#define IMG_H 1600.0f
#define IMG_W 2560.0f
#define NHBINS 32768
#define NWORDS 94               // ceil(6000/64)
#define NSORT 6016              // 94*64

// padded X: 102 rows x 162 cols x 512 ch
#define PR 102
#define PC 162
#define NPAD ((size_t)PR*PC*512)   // 8,460,288 ushorts per array

// prep_k grid layout
#define PB_SX   8000                       // split_x blocks
#define PB_SW   576                        // split_w blocks
#define PB_SW2  96                         // split_w2 blocks
#define PB_HZ   32                         // hist-zero blocks
#define NBORD   524                        // border pixels (2*PC + 2*(PR-2))
#define PB_BZ   262                        // border-zero blocks: 524*64*2/256
#define PB_TOT  (PB_SX+PB_SW+PB_SW2+PB_HZ+PB_BZ)   // 8966

typedef __attribute__((ext_vector_type(8))) _Float16 half8;
typedef __attribute__((ext_vector_type(4))) float floatx4;

__device__ __forceinline__ unsigned short f2h_hi(float x) {
    _Float16 h = (_Float16)x;
    return __builtin_bit_cast(unsigned short, h);
}
__device__ __forceinline__ unsigned short f2h_lo(float x, unsigned short hbits) {
    _Float16 h = __builtin_bit_cast(_Float16, hbits);
    _Float16 l = (_Float16)((x - (float)h) * 2048.0f);   // scaled residual: stays normal
    return __builtin_bit_cast(unsigned short, l);
}

#define GLL16(g, l) __builtin_amdgcn_global_load_lds( \
    (const __attribute__((address_space(1))) void*)(g), \
    (__attribute__((address_space(3))) void*)(l), 16, 0, 0)

// ---- workspace layout (units: floats) ----
static const size_t OYREG = 0;
static const size_t OXH   = OYREG + (size_t)NPIX * CONV_C;  // Xh ushorts; dead after conv
static const size_t OXL   = OXH + NPAD / 2;                 // Xl ushorts; dead after conv
static const size_t OWH   = OXL + NPAD / 2;                 // fp16 [9][n=512][k=512]
static const size_t OWL   = OWH + (size_t)9*512*512/2;
static const size_t ORAW  = OWL + (size_t)9*512*512/2;
static const size_t ONMS  = ORAW + NBOX;
static const size_t OPY1  = ONMS + NBOX;
static const size_t OPX1  = OPY1 + NBOX;
static const size_t OPY2  = OPX1 + NBOX;
static const size_t OPX2  = OPY2 + NBOX;
static const size_t OHIST = OPX2 + NBOX;                    // 32768 uints
static const size_t OCNT  = OHIST + NHBINS;                 // 4 ints
static const size_t OPAR  = OCNT + 4;                       // 2 ints
static const size_t OCS   = OPAR + 2;                       // 6000
static const size_t OCY1  = OCS + PRE_NMS;
static const size_t OCX1  = OCY1 + PRE_NMS;
static const size_t OCY2  = OCX1 + PRE_NMS;
static const size_t OCX2  = OCY2 + PRE_NMS;
static const size_t OW2H  = OCX2 + PRE_NMS;                 // 48*512 ushorts = 12288 floats
static const size_t OW2L  = OW2H + 12288;
// overlays (written after conv_mfma is done):
static const size_t OMASK = OXH;                            // u64[6016*94]
static const size_t OSY1  = OXL;                            // 6016 each, 5 arrays
static const size_t OSX1  = OSY1 + NSORT;
static const size_t OSY2  = OSX1 + NSORT;
static const size_t OSX2  = OSY2 + NSORT;
static const size_t OSAR  = OSX2 + NSORT;

// ============================================================
// prep_k: fused preprocessing (r8-verified)
// ============================================================
__global__ __launch_bounds__(256) void prep_k(
    const float* __restrict__ X, const float* __restrict__ W1,
    const float* __restrict__ Wc, const float* __restrict__ Wr,
    unsigned short* __restrict__ Xh, unsigned short* __restrict__ Xl,
    unsigned short* __restrict__ Wh, unsigned short* __restrict__ Wl,
    unsigned short* __restrict__ W2h, unsigned short* __restrict__ W2l,
    unsigned int* __restrict__ hist)
{
    __shared__ unsigned short Lh[64 * 64];
    __shared__ unsigned short Ll[64 * 64];
    const int B = blockIdx.x;
    const int t = threadIdx.x;

    if (B < PB_SX) {
        const int idx = B * 256 + t;
        const int p = idx >> 7;
        const int kq = (idx & 127) * 4;
        const float4 v = *(const float4*)(X + (size_t)p * 512 + kq);
        const int r = p / WFD, c = p % WFD;
        const size_t dst = ((size_t)(r + 1) * PC + (c + 1)) * 512 + kq;
        float vv[4] = { v.x, v.y, v.z, v.w };
        unsigned short h[4], lo[4];
        #pragma unroll
        for (int u = 0; u < 4; ++u) {
            h[u]  = f2h_hi(vv[u]);
            lo[u] = f2h_lo(vv[u], h[u]);
        }
        uint2 ph, pl;
        ph.x = (unsigned)h[0]  | ((unsigned)h[1]  << 16);
        ph.y = (unsigned)h[2]  | ((unsigned)h[3]  << 16);
        pl.x = (unsigned)lo[0] | ((unsigned)lo[1] << 16);
        pl.y = (unsigned)lo[2] | ((unsigned)lo[3] << 16);
        *(uint2*)(Xh + dst) = ph;
        *(uint2*)(Xl + dst) = pl;
    } else if (B < PB_SX + PB_SW) {
        const int blk = B - PB_SX;
        const int dydx = blk >> 6;
        const int rem  = blk & 63;
        const int k0 = (rem >> 3) * 64, n0 = (rem & 7) * 64;
        #pragma unroll
        for (int i = 0; i < 4; ++i) {
            const int f = t + 256 * i;
            const int row = f >> 4;
            const int cp  = (f & 15) * 4;
            const float4 v = *(const float4*)(W1 + ((size_t)(dydx * 512 + k0 + row)) * 512 + n0 + cp);
            float vv[4] = { v.x, v.y, v.z, v.w };
            #pragma unroll
            for (int u = 0; u < 4; ++u) {
                const unsigned short h = f2h_hi(vv[u]);
                Lh[(cp + u) * 64 + row] = h;
                Ll[(cp + u) * 64 + row] = f2h_lo(vv[u], h);
            }
        }
        __syncthreads();
        const int n  = t >> 2;
        const int kp = (t & 3) * 16;
        const size_t gbase = ((size_t)(dydx * 512 + n0 + n)) * 512 + k0 + kp;
        *(uint4*)(Wh + gbase)     = *(const uint4*)(Lh + n * 64 + kp);
        *(uint4*)(Wh + gbase + 8) = *(const uint4*)(Lh + n * 64 + kp + 8);
        *(uint4*)(Wl + gbase)     = *(const uint4*)(Ll + n * 64 + kp);
        *(uint4*)(Wl + gbase + 8) = *(const uint4*)(Ll + n * 64 + kp + 8);
    } else if (B < PB_SX + PB_SW + PB_SW2) {
        const int i = (B - PB_SX - PB_SW) * 256 + t;   // 0..24575
        if (i < 48 * 512) {
            const int n = i >> 9, k = i & 511;
            float v = 0.f;
            if (n < 9) v = Wc[k * 9 + n];
            else if (n < 45) v = Wr[k * 36 + (n - 9)];
            const unsigned short h = f2h_hi(v);
            W2h[i] = h;
            W2l[i] = f2h_lo(v, h);
        }
    } else if (B < PB_SX + PB_SW + PB_SW2 + PB_HZ) {
        for (int i = (B - PB_SX - PB_SW - PB_SW2) * 256 + t; i < NHBINS + 8; i += PB_HZ * 256)
            hist[i] = 0u;
    } else {
        const int s = (B - PB_SX - PB_SW - PB_SW2 - PB_HZ) * 256 + t;
        if (s < NBORD * 64 * 2) {
            const int arr = (s >= NBORD * 64) ? 1 : 0;
            const int si  = arr ? s - NBORD * 64 : s;
            const int pix = si >> 6, chunk = si & 63;
            int r, c;
            if (pix < PC)            { r = 0;                      c = pix; }
            else if (pix < 2 * PC)   { r = PR - 1;                 c = pix - PC; }
            else if (pix < 2 * PC + (PR - 2)) { r = 1 + (pix - 2 * PC);            c = 0; }
            else                     { r = 1 + (pix - 2 * PC - (PR - 2)); c = PC - 1; }
            unsigned short* dstA = arr ? Xl : Xh;
            uint4 z; z.x = 0u; z.y = 0u; z.z = 0u; z.w = 0u;
            *(uint4*)(dstA + ((size_t)r * PC + c) * 512 + chunk * 8) = z;
        }
    }
}

// ============================================================
// conv 3x3 512->512, split-fp16 3-pass MFMA.
// r2/r3/r7/r8-VERIFIED structure (bit-exact): XOR chunk swizzle keeps
// staging coalesced AND ds_read conflict-free; double-buffered with
// counted vmcnt(8); two barriers per K-step. Custom barrier schedules
// (r6 single-barrier, r9 4-phase) both hung the device — parked.
// ============================================================
__global__ __launch_bounds__(256, 2) void conv_mfma(
    const unsigned short* __restrict__ Xh, const unsigned short* __restrict__ Xl,
    const unsigned short* __restrict__ Wh, const unsigned short* __restrict__ Wl,
    const float* __restrict__ b1,
    unsigned short* __restrict__ Yh, unsigned short* __restrict__ Yl)
{
    __shared__ alignas(16) unsigned short Ah[2][128 * 32];
    __shared__ alignas(16) unsigned short Al[2][128 * 32];
    __shared__ alignas(16) unsigned short Bh[2][128 * 32];
    __shared__ alignas(16) unsigned short Bl[2][128 * 32];

    const int tid = threadIdx.x;
    const int w = tid >> 6, l = tid & 63;
    const int wy = w >> 1, wx = w & 1;

    const int bx = blockIdx.x;
    const int q = bx & 7, s5 = bx >> 3;
    const int tile = (q < 5) ? (q * 16 + s5) : (80 + (q - 5) * 15 + s5);
    const int pm0 = tile * 128, oc0 = blockIdx.y * 128;

    // staging offsets: row = l>>2 (coalesced), chunk XOR-swizzled in-line
    const int swW = ((l & 3) ^ ((l >> 3) & 3)) * 8;   // write-side chunk (ushorts)
    int aoff[2], boff[2], ldsOff[2];
    #pragma unroll
    for (int i = 0; i < 2; ++i) {
        const int m = w * 32 + i * 16 + (l >> 2);
        const int p = pm0 + m;
        const int r = p / WFD, c = p % WFD;
        aoff[i] = ((r + 1) * PC + (c + 1)) * 512 + swW;
        boff[i] = (oc0 + m) * 512 + swW;
        ldsOff[i] = (w * 32 + i * 16) * 32;
    }

    // fragment read offsets: row_in_region = l&15, chunk = (l>>4)^((l>>1)&3)
    const int swR = (((l >> 4) ^ ((l >> 1) & 3))) * 8;
    int afrag[4], bfrag[4];
    #pragma unroll
    for (int i = 0; i < 4; ++i) {
        afrag[i] = (wy * 64 + i * 16 + (l & 15)) * 32 + swR;
        bfrag[i] = (wx * 64 + i * 16 + (l & 15)) * 32 + swR;
    }

    floatx4 acc[4][4], accL[4][4];
    #pragma unroll
    for (int j = 0; j < 4; ++j) {
        const float bv = b1[oc0 + wx * 64 + j * 16 + (l & 15)];
        #pragma unroll
        for (int i = 0; i < 4; ++i) {
            acc[i][j][0] = bv; acc[i][j][1] = bv; acc[i][j][2] = bv; acc[i][j][3] = bv;
            accL[i][j][0] = 0.f; accL[i][j][1] = 0.f; accL[i][j][2] = 0.f; accL[i][j][3] = 0.f;
        }
    }

    #define CSTAGE(bf, dAx, dBx)                                    \
        _Pragma("unroll")                                           \
        for (int i = 0; i < 2; ++i) {                               \
            GLL16(Xh + aoff[i] + (dAx), Ah[bf] + ldsOff[i]);        \
            GLL16(Xl + aoff[i] + (dAx), Al[bf] + ldsOff[i]);        \
            GLL16(Wh + boff[i] + (dBx), Bh[bf] + ldsOff[i]);        \
            GLL16(Wl + boff[i] + (dBx), Bl[bf] + ldsOff[i]);        \
        }

    // prologue: stage step 0 (dydx=0 -> dy=-1,dx=-1; k0=0) into buffer 0
    CSTAGE(0, (-PC - 1) * 512, 0);

    for (int step = 0; step < 144; ++step) {
        const int cur = step & 1;
        if (step < 143) {
            const int s1 = step + 1;
            const int d1 = s1 >> 4;
            const int k1 = (s1 & 15) << 5;
            const int dy = d1 / 3 - 1, dx = d1 % 3 - 1;
            CSTAGE(cur ^ 1, (dy * PC + dx) * 512 + k1, d1 * (512 * 512) + k1);
            asm volatile("s_waitcnt vmcnt(8)" ::: "memory");
        } else {
            asm volatile("s_waitcnt vmcnt(0)" ::: "memory");
        }
        __builtin_amdgcn_s_barrier();
        asm volatile("" ::: "memory");

        const unsigned short* Ac = Ah[cur];
        const unsigned short* Lc = Al[cur];
        const unsigned short* Bc = Bh[cur];
        const unsigned short* Mc = Bl[cur];
        half8 fah[4], fal[4], fbh[4], fbl[4];
        #pragma unroll
        for (int i = 0; i < 4; ++i) {
            fah[i] = *(const half8*)(Ac + afrag[i]);
            fal[i] = *(const half8*)(Lc + afrag[i]);
            fbh[i] = *(const half8*)(Bc + bfrag[i]);
            fbl[i] = *(const half8*)(Mc + bfrag[i]);
        }
        #pragma unroll
        for (int i = 0; i < 4; ++i)
            #pragma unroll
            for (int j = 0; j < 4; ++j) {
                acc[i][j]  = __builtin_amdgcn_mfma_f32_16x16x32_f16(fah[i], fbh[j], acc[i][j], 0, 0, 0);
                accL[i][j] = __builtin_amdgcn_mfma_f32_16x16x32_f16(fal[i], fbh[j], accL[i][j], 0, 0, 0);
                accL[i][j] = __builtin_amdgcn_mfma_f32_16x16x32_f16(fah[i], fbl[j], accL[i][j], 0, 0, 0);
            }
        asm volatile("" ::: "memory");
        __builtin_amdgcn_s_barrier();
    }
    #undef CSTAGE

    // epilogue: ReLU + fp16 hi/lo split + store
    #pragma unroll
    for (int i = 0; i < 4; ++i) {
        const int row0 = pm0 + wy * 64 + i * 16 + (l >> 4) * 4;
        #pragma unroll
        for (int j = 0; j < 4; ++j) {
            const int col = oc0 + wx * 64 + j * 16 + (l & 15);
            #pragma unroll
            for (int r = 0; r < 4; ++r) {
                const float yv = fmaxf(acc[i][j][r] + accL[i][j][r] * 4.8828125e-4f, 0.f);
                const unsigned short h = f2h_hi(yv);
                const size_t o = (size_t)(row0 + r) * 512 + col;
                Yh[o] = h;
                Yl[o] = f2h_lo(yv, h);
            }
        }
    }
}

// ============================================================
// heads as skinny split-fp16 MFMA GEMM (r3-verified, LDS histogram).
// ============================================================
__global__ __launch_bounds__(256) void heads_mfma(
    const unsigned short* __restrict__ Yh, const unsigned short* __restrict__ Yl,
    const unsigned short* __restrict__ W2h, const unsigned short* __restrict__ W2l,
    const float* __restrict__ bc, const float* __restrict__ br,
    const float* __restrict__ anch,
    float* __restrict__ out_scores, float* __restrict__ out_deltas,
    float* __restrict__ rawS, float* __restrict__ nmsS,
    float* __restrict__ pY1, float* __restrict__ pX1,
    float* __restrict__ pY2, float* __restrict__ pX2,
    unsigned int* __restrict__ hist)
{
    __shared__ alignas(16) unsigned short Ah[128 * 32];
    __shared__ alignas(16) unsigned short Al[128 * 32];
    __shared__ alignas(16) unsigned short Bh[48 * 32];
    __shared__ alignas(16) unsigned short Bl[48 * 32];
    __shared__ float Lg[128 * 49];
    __shared__ unsigned int Hh[NHBINS / 2];   // packed u16-pair histogram, 64KB

    const int tid = threadIdx.x;
    const int w = tid >> 6, l = tid & 63;
    const int pm0 = blockIdx.x * 128;

    #pragma unroll 4
    for (int i = tid; i < NHBINS / 2; i += 256) Hh[i] = 0u;

    const int swW = ((l & 3) ^ ((l >> 3) & 3)) * 8;
    int aoff[2], ldsOff[2];
    #pragma unroll
    for (int i = 0; i < 2; ++i) {
        const int m = w * 32 + i * 16 + (l >> 2);
        aoff[i] = (pm0 + m) * 512 + swW;
        ldsOff[i] = (w * 32 + i * 16) * 32;
    }
    const int bglb = (w * 16 + (l >> 2)) * 512 + swW;  // valid for w<3
    const int blds = w * 16 * 32;

    const int swR = (((l >> 4) ^ ((l >> 1) & 3))) * 8;
    int afrag[2], bfrag[3];
    #pragma unroll
    for (int i = 0; i < 2; ++i)
        afrag[i] = (w * 32 + i * 16 + (l & 15)) * 32 + swR;
    #pragma unroll
    for (int j = 0; j < 3; ++j)
        bfrag[j] = (j * 16 + (l & 15)) * 32 + swR;

    floatx4 acc[2][3], accL[2][3];
    #pragma unroll
    for (int i = 0; i < 2; ++i)
        #pragma unroll
        for (int j = 0; j < 3; ++j) {
            acc[i][j][0] = 0.f; acc[i][j][1] = 0.f; acc[i][j][2] = 0.f; acc[i][j][3] = 0.f;
            accL[i][j] = acc[i][j];
        }

    for (int k0 = 0; k0 < 512; k0 += 32) {
        __syncthreads();
        #pragma unroll
        for (int i = 0; i < 2; ++i) {
            GLL16(Yh + aoff[i] + k0, Ah + ldsOff[i]);
            GLL16(Yl + aoff[i] + k0, Al + ldsOff[i]);
        }
        if (w < 3) {
            GLL16(W2h + bglb + k0, Bh + blds);
            GLL16(W2l + bglb + k0, Bl + blds);
        }
        __syncthreads();
        half8 fah[2], fal[2], fbh[3], fbl[3];
        #pragma unroll
        for (int i = 0; i < 2; ++i) {
            fah[i] = *(const half8*)(Ah + afrag[i]);
            fal[i] = *(const half8*)(Al + afrag[i]);
        }
        #pragma unroll
        for (int j = 0; j < 3; ++j) {
            fbh[j] = *(const half8*)(Bh + bfrag[j]);
            fbl[j] = *(const half8*)(Bl + bfrag[j]);
        }
        #pragma unroll
        for (int i = 0; i < 2; ++i)
            #pragma unroll
            for (int j = 0; j < 3; ++j) {
                acc[i][j]  = __builtin_amdgcn_mfma_f32_16x16x32_f16(fah[i], fbh[j], acc[i][j], 0, 0, 0);
                accL[i][j] = __builtin_amdgcn_mfma_f32_16x16x32_f16(fal[i], fbh[j], accL[i][j], 0, 0, 0);
                accL[i][j] = __builtin_amdgcn_mfma_f32_16x16x32_f16(fah[i], fbl[j], accL[i][j], 0, 0, 0);
            }
    }

    __syncthreads();
    #pragma unroll
    for (int i = 0; i < 2; ++i) {
        const int prow0 = w * 32 + i * 16 + (l >> 4) * 4;
        #pragma unroll
        for (int j = 0; j < 3; ++j) {
            const int col = j * 16 + (l & 15);
            #pragma unroll
            for (int r = 0; r < 4; ++r)
                Lg[(prow0 + r) * 49 + col] = acc[i][j][r] + accL[i][j][r] * 4.8828125e-4f;
        }
    }
    __syncthreads();

    if (tid < 128) {
        const int p = pm0 + tid;
        float ac[9], arr[36];
        #pragma unroll
        for (int a = 0; a < 9; ++a) ac[a] = Lg[tid * 49 + a] + bc[a];
        #pragma unroll
        for (int j = 0; j < 36; ++j) arr[j] = Lg[tid * 49 + 9 + j] + br[j];

        float m = ac[0];
        #pragma unroll
        for (int a = 1; a < 9; ++a) m = fmaxf(m, ac[a]);
        float s = 0.f, e[9];
        #pragma unroll
        for (int a = 0; a < 9; ++a) { e[a] = expf(ac[a] - m); s += e[a]; }
        #pragma unroll
        for (int a = 0; a < 9; ++a) e[a] = e[a] / s;

        #pragma unroll
        for (int a = 0; a < 9; ++a) out_scores[p * 9 + a] = e[a];
        #pragma unroll
        for (int a = 0; a < 9; ++a)
            *(float4*)(out_deltas + (size_t)p * 36 + 4 * a) =
                make_float4(arr[4*a], arr[4*a+1], arr[4*a+2], arr[4*a+3]);

        #pragma unroll
        for (int a = 0; a < 9; ++a) {
            const float4 an = *(const float4*)(anch + (size_t)p * 36 + 4 * a);
            const float cty = an.x + arr[4*a]   * an.z;
            const float ctx = an.y + arr[4*a+1] * an.w;
            const float szy = an.z * expf(arr[4*a+2]);
            const float szx = an.w * expf(arr[4*a+3]);
            float y1 = fmaxf(cty - 0.5f * szy, 0.f);
            float x1 = fmaxf(ctx - 0.5f * szx, 0.f);
            float y2 = fminf(cty + 0.5f * szy, IMG_H);
            float x2 = fminf(ctx + 0.5f * szx, IMG_W);
            const bool valid = ((y2 - y1) >= 16.f) && ((x2 - x1) >= 16.f);
            const int idx = p * 9 + a;
            rawS[idx] = e[a];
            nmsS[idx] = valid ? e[a] : NEGV;
            pY1[idx] = y1; pX1[idx] = x1; pY2[idx] = y2; pX2[idx] = x2;
            const unsigned b = __float_as_uint(e[a]) >> 15;
            atomicAdd(&Hh[b >> 1], (b & 1) ? 65536u : 1u);
        }
    }

    __syncthreads();
    for (int i = tid; i < NHBINS / 2; i += 256) {
        const unsigned v = Hh[i];
        if (v) {
            const unsigned lo = v & 0xFFFFu;
            const unsigned hi = v >> 16;
            if (lo) atomicAdd(&hist[2 * i],     lo);
            if (hi) atomicAdd(&hist[2 * i + 1], hi);
        }
    }
}

// ============================================================
// select_k: parallel suffix-scan over histogram
// ============================================================
__global__ __launch_bounds__(1024) void select_k(const unsigned int* __restrict__ hist,
                                                 int* __restrict__ params)
{
    __shared__ unsigned int ps[1024];
    const int t = threadIdx.x;
    unsigned int loc[32];
    unsigned int sum = 0;
    #pragma unroll 4
    for (int i = 0; i < 32; ++i) { loc[i] = hist[t * 32 + i]; sum += loc[i]; }
    ps[t] = sum;
    for (int off = 1; off < 1024; off <<= 1) {
        __syncthreads();
        const unsigned int add = (t + off < 1024) ? ps[t + off] : 0u;
        __syncthreads();
        ps[t] += add;
    }
    __syncthreads();
    const unsigned int above = (t < 1023) ? ps[t + 1] : 0u;
    if (above < (unsigned)PRE_NMS && ps[t] >= (unsigned)PRE_NMS) {
        unsigned int cum = above;
        for (int j = 31; j >= 0; --j) {
            const unsigned int h = loc[j];
            if (cum + h >= (unsigned)PRE_NMS) {
                params[0] = t * 32 + j;
                params[1] = PRE_NMS - (int)cum;
                break;
            }
            cum += h;
        }
    }
}

// ============================================================
// compact_k (r3-verified simple version)
// ============================================================
__global__ void compact_k(const float* __restrict__ rawS, const float* __restrict__ nmsS,
                          const float* __restrict__ pY1, const float* __restrict__ pX1,
                          const float* __restrict__ pY2, const float* __restrict__ pX2,
                          const int* __restrict__ params, int* __restrict__ cnts,
                          float* __restrict__ cS,
                          float* __restrict__ cY1, float* __restrict__ cX1,
                          float* __restrict__ cY2, float* __restrict__ cX2)
{
    const int i = blockIdx.x * 256 + threadIdx.x;
    if (i >= NBOX) return;
    const int b = (int)(__float_as_uint(rawS[i]) >> 15);
    const int bin = params[0];
    const int need = params[1];
    int pos = -1;
    if (b > bin) {
        pos = atomicAdd(&cnts[0], 1);
    } else if (b == bin) {
        const int t2 = atomicAdd(&cnts[1], 1);
        if (t2 < need) pos = atomicAdd(&cnts[0], 1);
    }
    if (pos >= 0) {
        const float sv = nmsS[i];
        cS[pos]  = sv;
        cY1[pos] = pY1[i]; cX1[pos] = pX1[i];
        cY2[pos] = pY2[i]; cX2[pos] = pX2[i];
        if (sv > NEGV * 0.5f) atomicAdd(&cnts[2], 1);
    }
}

// ============================================================
// sort_k (r3-verified bitonic): sort by score desc, gather SoA boxes
// ============================================================
__global__ __launch_bounds__(1024) void sort_k(
    const float* __restrict__ cS,
    const float* __restrict__ cY1, const float* __restrict__ cX1,
    const float* __restrict__ cY2, const float* __restrict__ cX2,
    float* __restrict__ sY1, float* __restrict__ sX1,
    float* __restrict__ sY2, float* __restrict__ sX2,
    float* __restrict__ sAr)
{
    __shared__ unsigned long long keys[8192];
    const int t = threadIdx.x;
    for (int i = t; i < 8192; i += 1024) {
        unsigned long long k;
        if (i < PRE_NMS) {
            const unsigned b = __float_as_uint(cS[i]);
            const unsigned m = (b & 0x80000000u) ? ~b : (b | 0x80000000u);
            k = ((unsigned long long)(~m) << 32) | (unsigned)i;
        } else {
            k = ~0ULL;
        }
        keys[i] = k;
    }
    for (int kk = 2; kk <= 8192; kk <<= 1) {
        for (int j = kk >> 1; j > 0; j >>= 1) {
            __syncthreads();
            for (int t4 = t; t4 < 4096; t4 += 1024) {
                const int i  = ((t4 & ~(j - 1)) << 1) | (t4 & (j - 1));
                const int p2 = i | j;
                const bool up = ((i & kk) == 0);
                const unsigned long long a = keys[i], b = keys[p2];
                const bool sw = up ? (a > b) : (a < b);
                if (sw) { keys[i] = b; keys[p2] = a; }
            }
        }
    }
    __syncthreads();
    for (int i = t; i < NSORT; i += 1024) {
        if (i < PRE_NMS) {
            const int j = (int)(keys[i] & 0xFFFFFFFFu);
            const float y1 = cY1[j], x1 = cX1[j], y2 = cY2[j], x2 = cX2[j];
            sY1[i] = y1; sX1[i] = x1; sY2[i] = y2; sX2[i] = x2;
            sAr[i] = (y2 - y1) * (x2 - x1);
        } else {
            sY1[i] = 0.f; sX1[i] = 0.f; sY2[i] = 0.f; sX2[i] = 0.f; sAr[i] = 0.f;
        }
    }
}

// ============================================================
// mask_k: suppression bitmask, UPPER TRIANGLE only (by >= bx).
// The greedy scan extracts suppression words monotonically: a pick in
// word w only ever reads columns >= w (same-word via the diagonal
// block, future words via r0/r1 whose past-word bits are never
// re-extracted). Lower-triangle blocks are dead work -> skipped;
// their mask region stays stale-garbage, OR'd only into past-word
// bits that are provably never read.
// ============================================================
__global__ __launch_bounds__(64) void mask_k(
    const float* __restrict__ sY1, const float* __restrict__ sX1,
    const float* __restrict__ sY2, const float* __restrict__ sX2,
    const float* __restrict__ sAr, unsigned long long* __restrict__ mask)
{
    if (blockIdx.y < blockIdx.x) return;   // uniform per block; no barrier after
    __shared__ float ly1[64], lx1[64], ly2[64], lx2[64], lar[64];
    const int t = threadIdx.x;
    const int c = blockIdx.y * 64 + t;
    ly1[t] = sY1[c]; lx1[t] = sX1[c]; ly2[t] = sY2[c]; lx2[t] = sX2[c]; lar[t] = sAr[c];
    __syncthreads();
    const int r = blockIdx.x * 64 + t;
    const float ry1 = sY1[r], rx1 = sX1[r], ry2 = sY2[r], rx2 = sX2[r], rar = sAr[r];
    unsigned long long bits = 0ULL;
    #pragma unroll 8
    for (int u = 0; u < 64; ++u) {
        const float iy1 = fmaxf(ry1, ly1[u]);
        const float ix1 = fmaxf(rx1, lx1[u]);
        const float iy2 = fminf(ry2, ly2[u]);
        const float ix2 = fminf(rx2, lx2[u]);
        const float inter = fmaxf(iy2 - iy1, 0.f) * fmaxf(ix2 - ix1, 0.f);
        const float iou = inter / (lar[u] + rar - inter + 1e-8f);
        bits |= (iou > 0.7f) ? (1ULL << u) : 0ULL;
    }
    mask[(size_t)r * NWORDS + blockIdx.y] = bits;
}

// ============================================================
// scan2_k (r3-verified structure): chunked-LDS greedy scan, one wave.
// NEW: word-diagonal hoisted into registers (diag = rows[l][w], lane l
// holds row l's word-w entry) so the per-pick same-word suppression
// `cw |= rows[b][w]` (a ~120cyc dependent LDS broadcast on the serial
// greedy chain) becomes `cw |= __shfl(diag, b)` (~30cyc). Exactly
// equivalent: rows[] is immutable between stagings.
// ============================================================
__global__ __launch_bounds__(64) void scan2_k(
    const float* __restrict__ sY1, const float* __restrict__ sX1,
    const float* __restrict__ sY2, const float* __restrict__ sX2,
    const unsigned long long* __restrict__ mask, const int* __restrict__ cnts,
    float* __restrict__ outP)
{
    __shared__ alignas(16) unsigned long long rows[64][96];
    const int l = threadIdx.x;
    const int nvRaw = cnts[2];
    const int nv = nvRaw < PRE_NMS ? nvRaw : PRE_NMS;
    unsigned long long r0 = 0ULL, r1 = 0ULL;
    int n = 0;
    for (int w = 0; w < NWORDS; ++w) {
        const int base = w << 6;
        if (base >= nv || n >= POST_NMS) break;
        for (int r = 0; r < 64; ++r) {
            if (l < 47)
                GLL16(mask + (size_t)(base + r) * NWORDS + 2 * l, &rows[r][0]);
        }
        const int ci = base + l;
        const float v1 = sY1[ci], v2 = sX1[ci], v3 = sY2[ci], v4 = sX2[ci];
        __syncthreads();
        const unsigned long long diag = rows[l][w];   // row l's word-w entry
        unsigned long long cw = (w < 64) ? __shfl(r0, w, 64) : __shfl(r1, w - 64, 64);
        const int lim = nv - base;
        if (lim < 64) cw |= (~0ULL << lim);
        while (cw != ~0ULL && n < POST_NMS) {
            const int b = (int)__builtin_ctzll(~cw);
            const float by1 = __shfl(v1, b, 64);
            const float bx1 = __shfl(v2, b, 64);
            const float by2 = __shfl(v3, b, 64);
            const float bx2 = __shfl(v4, b, 64);
            if (l == 0) {
                outP[4 * n + 0] = by1; outP[4 * n + 1] = bx1;
                outP[4 * n + 2] = by2; outP[4 * n + 3] = bx2;
            }
            ++n;
            cw |= (1ULL << b);
            if (n >= POST_NMS) break;
            r0 |= rows[b][l];
            if (l < NWORDS - 64) r1 |= rows[b][64 + l];
            cw |= __shfl(diag, b, 64);                // == rows[b][w]
        }
        __syncthreads();
    }
    for (int idx = 4 * n + l; idx < 4 * POST_NMS; idx += 64) outP[idx] = 0.f;
}

// ============================================================
extern "C" void kernel_launch(void* const* d_in, const int* in_sizes, int n_in,
                              void* d_out, int out_size, void* d_ws, size_t ws_size,
                              hipStream_t stream)
{
    const float* X    = (const float*)d_in[1];
    const float* anch = (const float*)d_in[2];
    const float* W1   = (const float*)d_in[3];
    const float* b1   = (const float*)d_in[4];
    const float* Wc   = (const float*)d_in[5];
    const float* bc   = (const float*)d_in[6];
    const float* Wr   = (const float*)d_in[7];
    const float* br   = (const float*)d_in[8];

    float* out = (float*)d_out;
    float* ws  = (float*)d_ws;

    unsigned short* Yh = (unsigned short*)(ws + OYREG);
    unsigned short* Yl = Yh + (size_t)NPIX * CONV_C;
    unsigned short* Xh = (unsigned short*)(ws + OXH);
    unsigned short* Xl = (unsigned short*)(ws + OXL);
    unsigned short* Wh = (unsigned short*)(ws + OWH);
    unsigned short* Wl = (unsigned short*)(ws + OWL);
    float* rawS = ws + ORAW;
    float* nmsS = ws + ONMS;
    float* pY1  = ws + OPY1;
    float* pX1  = ws + OPX1;
    float* pY2  = ws + OPY2;
    float* pX2  = ws + OPX2;
    unsigned int* hist = (unsigned int*)(ws + OHIST);
    int* cnts   = (int*)(ws + OCNT);
    int* params = (int*)(ws + OPAR);
    float* cS   = ws + OCS;
    float* cY1  = ws + OCY1;
    float* cX1  = ws + OCX1;
    float* cY2  = ws + OCY2;
    float* cX2  = ws + OCX2;
    unsigned short* W2h = (unsigned short*)(ws + OW2H);
    unsigned short* W2l = (unsigned short*)(ws + OW2L);
    float* sY1  = ws + OSY1;
    float* sX1  = ws + OSX1;
    float* sY2  = ws + OSY2;
    float* sX2  = ws + OSX2;
    float* sAr  = ws + OSAR;
    unsigned long long* mask = (unsigned long long*)(ws + OMASK);

    float* out_scores = out;
    float* out_deltas = out + NBOX;
    float* out_props  = out + (size_t)NBOX * 5;

    prep_k<<<PB_TOT, 256, 0, stream>>>(X, W1, Wc, Wr,
                                       Xh, Xl, Wh, Wl, W2h, W2l, hist);

    conv_mfma<<<dim3(125, 4), 256, 0, stream>>>(Xh, Xl, Wh, Wl, b1, Yh, Yl);

    heads_mfma<<<125, 256, 0, stream>>>(Yh, Yl, W2h, W2l, bc, br, anch,
        out_scores, out_deltas, rawS, nmsS, pY1, pX1, pY2, pX2, hist);

    select_k<<<1, 1024, 0, stream>>>(hist, params);
    compact_k<<<(NBOX + 255) / 256, 256, 0, stream>>>(
        rawS, nmsS, pY1, pX1, pY2, pX2, params, cnts, cS, cY1, cX1, cY2, cX2);

    sort_k<<<1, 1024, 0, stream>>>(cS, cY1, cX1, cY2, cX2,
                                   sY1, sX1, sY2, sX2, sAr);
    mask_k<<<dim3(NWORDS, NWORDS), 64, 0, stream>>>(sY1, sX1, sY2, sX2, sAr, mask);
    scan2_k<<<1, 64, 0, stream>>>(sY1, sX1, sY2, sX2, mask, cnts, out_props);
}